// Round 8
// baseline (8188.623 us; speedup 1.0000x reference)
//
#include <hip/hip_runtime.h>
#include <hip/hip_bf16.h>
#include <math.h>

typedef unsigned short u16;
typedef __attribute__((ext_vector_type(8))) short bf16x8;
typedef __attribute__((ext_vector_type(4))) float f32x4;
typedef __attribute__((ext_vector_type(16))) float f32x16;

#define IN_CH   256
#define STATE   384
#define OUT_SEQ 32
#define B_SZ    8
#define SEQ     512
#define M_ROWS  4096
#define NJ      768   // 2*STATE

// plane sizes (elements)
#define PS_WB  (NJ*IN_CH)      // 196608
#define PS_WC  (IN_CH*NJ)      // 196608
#define PS_WD  (IN_CH*IN_CH)   // 65536

// ---------------- workspace layout (bytes) ----------------
static constexpr size_t B_U   = 0;                                   // U / 4 partials
static constexpr size_t B_Z   = B_U  + 8*(size_t)M_ROWS*IN_CH*4;
static constexpr size_t B_XA  = B_Z  + 3*(size_t)M_ROWS*NJ*2;
static constexpr size_t B_XB  = B_XA + 3*(size_t)M_ROWS*IN_CH*2;
static constexpr size_t B_WB  = B_XB + 3*(size_t)M_ROWS*IN_CH*2;
static constexpr size_t B_WC  = B_WB + 3*(size_t)PS_WB*2;
static constexpr size_t B_WD  = B_WC + 3*(size_t)PS_WC*2;
static constexpr size_t B_LAM = B_WD + 3*(size_t)PS_WD*2;            // lam, lam64
static constexpr size_t B_HC  = B_LAM + 2*768*4;                     // Hc0, Hc1
static constexpr size_t B_CAR = B_HC  + 2*(size_t)B_SZ*NJ*4;         // carries
static constexpr size_t B_CNT = B_CAR + (size_t)B_SZ*8*STATE*8;      // counters

#define NCNT1 96      // per-iter gemm1 counters (8 b x 12 ntile)
#define NCNT2 128     // per-iter gemm2 counters (32 mtile x 4 ntile)

// ---------------- helpers ----------------
__device__ __forceinline__ u16 f2b(float v) {
    __hip_bfloat16 h = __float2bfloat16(v);
    return *(u16*)&h;
}
__device__ __forceinline__ float b2f(u16 u) {
    __hip_bfloat16 h = *(__hip_bfloat16*)&u;
    return __bfloat162float(h);
}
__device__ __forceinline__ void split3(float v, u16& a, u16& b, u16& c) {
    a = f2b(v);  float r1 = v  - b2f(a);
    b = f2b(r1); float r2 = r1 - b2f(b);
    c = f2b(r2);
}
__device__ __forceinline__ void gload_lds16(const void* g, void* l) {
    __builtin_amdgcn_global_load_lds(
        (const __attribute__((address_space(1))) void*)g,
        (__attribute__((address_space(3))) void*)l, 16, 0, 0);
}

// fragment-index decode: r (within one c32 block) -> (t32,h,hi5,lo5,e)
__device__ __forceinline__ void frag_decode(int r, int& t32, int& h, int& hi5,
                                            int& lo5, int& e) {
    t32 = r >> 10; int r2 = r & 1023;
    h = r2 >> 9;   int r3 = r2 & 511;
    hi5 = r3 >> 8; int r4 = r3 & 255;
    lo5 = r4 >> 3; e = r4 & 7;
}

// ---------------- prep kernels ----------------
__global__ void prep_lam_hc(const float* __restrict__ nu_log,
                            const float* __restrict__ th_log,
                            float* __restrict__ lam, float* __restrict__ lam64,
                            float* __restrict__ hc0, int* __restrict__ cnt) {
    int n = threadIdx.x;
    if (n < STATE) {
        float lm = expf(-expf(nu_log[n]));
        float th = expf(th_log[n]);
        float ar = lm * cosf(th), ai = lm * sinf(th);
        lam[2*n] = ar; lam[2*n+1] = ai;
        float pr = ar, pi = ai;
#pragma unroll
        for (int i = 0; i < 6; ++i) {   // lambda^64
            float nr = pr*pr - pi*pi, ni = 2.f*pr*pi;
            pr = nr; pi = ni;
        }
        lam64[2*n] = pr; lam64[2*n+1] = pi;
    }
    for (int i = threadIdx.x; i < B_SZ*NJ; i += blockDim.x) hc0[i] = 0.f;
    for (int i = threadIdx.x; i < OUT_SEQ*(NCNT1 + NCNT2); i += blockDim.x) cnt[i] = 0;
}

// WB fragment-ordered: Ncols=768 (j), K=256. per-c32 block = 8192 elems, NT32=8.
__global__ void prep_wb(const float* __restrict__ B_re, const float* __restrict__ B_im,
                        const float* __restrict__ gamma_log, u16* __restrict__ W) {
    int idx = blockIdx.x*blockDim.x + threadIdx.x;   // < 196608
    int c32 = idx >> 13, r = idx & 8191;
    int t32,h,hi5,lo5,e; frag_decode(r, t32,h,hi5,lo5,e);
    int j = c32*32 + lo5;
    int k = t32*32 + (2*h + hi5)*8 + e;
    int n = j >> 1;
    float g = expf(gamma_log[n]);
    float v = g * ((j & 1) ? B_im[n*IN_CH + k] : B_re[n*IN_CH + k]);
    u16 a,b,cc; split3(v,a,b,cc);
    W[idx] = a; W[idx + PS_WB] = b; W[idx + 2*PS_WB] = cc;
}

// WC: Ncols=256 (o), K=768 (j): per-c32 block = 24576, NT32=24.
// WD: Ncols=256 (o), K=256 (c): per-c32 block = 8192,  NT32=8.
__global__ void prep_wcd(const float* __restrict__ C_re, const float* __restrict__ C_im,
                         const float* __restrict__ D,
                         u16* __restrict__ WC, u16* __restrict__ WD) {
    int idx = blockIdx.x*blockDim.x + threadIdx.x;   // < 196608 + 65536
    if (idx < PS_WC) {
        int c32 = idx / 24576, r = idx % 24576;
        int t32,h,hi5,lo5,e; frag_decode(r, t32,h,hi5,lo5,e);
        int o = c32*32 + lo5;
        int j = t32*32 + (2*h + hi5)*8 + e;
        int n = j >> 1;
        float v = (j & 1) ? -C_im[o*STATE + n] : C_re[o*STATE + n];
        u16 a,b,c; split3(v,a,b,c);
        WC[idx] = a; WC[idx + PS_WC] = b; WC[idx + 2*PS_WC] = c;
    } else {
        int q = idx - PS_WC;
        int c32 = q >> 13, r = q & 8191;
        int t32,h,hi5,lo5,e; frag_decode(r, t32,h,hi5,lo5,e);
        int o = c32*32 + lo5;
        int c = t32*32 + (2*h + hi5)*8 + e;
        float v = D[o*IN_CH + c];
        u16 a,b,cc; split3(v,a,b,cc);
        WD[q] = a; WD[q + PS_WD] = b; WD[q + 2*PS_WD] = cc;
    }
}

__global__ void prep_x(const float* __restrict__ x,
                       u16* __restrict__ X1, u16* __restrict__ X2, u16* __restrict__ X3) {
    int idx = blockIdx.x*blockDim.x + threadIdx.x;
    u16 a,b,c; split3(x[idx],a,b,c);
    X1[idx] = a; X2[idx] = b; X3[idx] = c;
}

// product order for bf16x3 (large terms first)
__device__ __constant__ const int cPI[6] = {0,0,1,0,1,2};
__device__ __constant__ const int cPJ[6] = {0,1,0,2,1,0};

// ---------------- GEMM1 + fused chunk-carry + last-block scan-emit ----------
// grid (64 m-tiles, 12 n-tiles). 64x64 tile, 4 waves, 32x32x16 MFMA,
// A-only LDS staging, B in regs (fragment-ordered). The 8th block per
// (b, n-tile) emits Z splits for all 8 chunks x 32 states.
struct G1P { const u16* A[3]; };

__global__ __launch_bounds__(256, 2)
void gemm1_k(G1P ga, const u16* __restrict__ WBp, float* __restrict__ Uout,
             const float* __restrict__ lam, const float* __restrict__ lam64,
             float2* __restrict__ carry,
             const float2* __restrict__ HcIn, float2* __restrict__ HcOut,
             u16* __restrict__ Z1, u16* __restrict__ Z2, u16* __restrict__ Z3,
             int* __restrict__ cnt) {
    __shared__ __align__(16) char smem[24576];   // 2 x 12KB (A dbuf)
    const int tid = threadIdx.x, lane = tid & 63, w = tid >> 6;
    const int wr = w & 1, wcq = w >> 1;
    const int m0 = blockIdx.x*64, n0 = blockIdx.y*64;
    const int hi5 = lane >> 5, lo5 = lane & 31;
    const int c32 = (n0 >> 5) + wcq;

    f32x16 acc;
#pragma unroll
    for (int i = 0; i < 16; ++i) acc[i] = 0.f;

    bf16x8 bwin[3][4][2];
    auto loadB = [&](int cw) {
#pragma unroll
        for (int p = 0; p < 3; ++p)
#pragma unroll
            for (int t = 0; t < 4; ++t)
#pragma unroll
                for (int h = 0; h < 2; ++h)
                    bwin[p][t][h] = *(const bf16x8*)(WBp + (size_t)p*PS_WB
                        + ((((size_t)(c32*8 + cw*4 + t)*2 + h)*2 + hi5) << 8) + lo5*8);
    };

    auto stageA = [&](int ks, int buf) {
        int kg = ks*32;
        char* L = smem + buf*12288;
#pragma unroll
        for (int r = 0; r < 3; ++r) {            // 768 chunks of 16B
            int q = tid + r*256;
            int p = q >> 8, cq = q & 255, o = cq >> 6, row = cq & 63;
            gload_lds16(ga.A[p] + (size_t)(m0 + row)*IN_CH + kg + o*8,
                        L + (size_t)q*16);
        }
    };

    stageA(0, 0);
    loadB(0);
    __syncthreads();
    int cur = 0;
#pragma unroll
    for (int ks = 0; ks < 8; ++ks) {
        if (ks == 4) loadB(1);
        if (ks + 1 < 8) stageA(ks + 1, cur ^ 1);
        const char* L = smem + cur*12288;
        bf16x8 av[3][2];
#pragma unroll
        for (int p = 0; p < 3; ++p)
#pragma unroll
            for (int h = 0; h < 2; ++h)
                av[p][h] = *(const bf16x8*)(L + p*4096 + (2*h + hi5)*1024
                                            + (wr*32 + lo5)*16);
        const int tw = ks & 3;
#pragma unroll
        for (int t6 = 0; t6 < 6; ++t6)
#pragma unroll
            for (int h = 0; h < 2; ++h)
                acc = __builtin_amdgcn_mfma_f32_32x32x16_bf16(
                    av[cPI[t6]][h], bwin[cPJ[t6]][tw][h], acc, 0, 0, 0);
        __syncthreads();
        cur ^= 1;
    }

    // epilogue: U to global + LDS tile
    float* Ls = (float*)smem;                     // [64][64] fp32 = 16KB
#pragma unroll
    for (int reg = 0; reg < 16; ++reg) {
        int rl = wr*32 + (reg & 3) + 8*(reg >> 2) + 4*hi5;
        int cl = wcq*32 + lo5;
        float v = acc[reg];
        Uout[(size_t)(m0 + rl)*NJ + n0 + cl] = v;
        Ls[rl*64 + cl] = v;
    }
    __syncthreads();

    // fused chunk carry: 32 threads, 64-step local scan from LDS tile
    const int b = m0 >> 9;
    if (tid < 32) {
        int ch = (m0 >> 6) & 7;
        int n = (n0 >> 1) + tid;
        float lre = lam[2*n], lim = lam[2*n+1];
        float hr = 0.f, hm = 0.f;
        const float2* L2 = (const float2*)smem;   // [64][32] float2
        float2 pf[8];
#pragma unroll
        for (int p = 0; p < 8; ++p) pf[p] = L2[p*32 + tid];
        for (int s0 = 0; s0 < 64; s0 += 8) {
#pragma unroll
            for (int p = 0; p < 8; ++p) {
                int st = s0 + p;
                float ur = pf[p].x, ui = pf[p].y;
                if (st + 8 < 64) pf[p] = L2[(st + 8)*32 + tid];
                float nr = fmaf(lre, hr, fmaf(-lim, hm, ur));
                float nm = fmaf(lre, hm, fmaf( lim, hr, ui));
                hr = nr; hm = nm;
            }
        }
        carry[(size_t)(b*8 + ch)*STATE + n] = make_float2(hr, hm);
    }

    // last-block ticket: 8th block for (b, ntile) emits Z
    __shared__ int s_old;
    __threadfence();
    __syncthreads();
    if (tid == 0) s_old = atomicAdd(&cnt[b*12 + blockIdx.y], 1);
    __syncthreads();
    if (s_old != 7) return;
    __threadfence();

    // emit: 256 threads = 8 chunks x 32 states
    {
        int s = tid & 31, c = tid >> 5;
        int n = blockIdx.y*32 + s;
        float lre = lam[2*n], lim = lam[2*n+1];
        float p64r = lam64[2*n], p64i = lam64[2*n+1];
        float2 h = HcIn[(size_t)b*STATE + n];
        for (int j = 0; j < c; ++j) {
            float2 cj = carry[(size_t)(b*8 + j)*STATE + n];
            float nr = fmaf(p64r, h.x, fmaf(-p64i, h.y, cj.x));
            float ni = fmaf(p64r, h.y, fmaf( p64i, h.x, cj.y));
            h.x = nr; h.y = ni;
        }
        const float2* U2 = (const float2*)Uout + (size_t)(b*SEQ + c*64)*STATE + n;
        size_t zb = (size_t)(b*SEQ + c*64)*NJ + 2*n;
        float2 buf[16];
#pragma unroll
        for (int p = 0; p < 16; ++p) buf[p] = U2[(size_t)p*STATE];
        for (int s0 = 0; s0 < 64; s0 += 16) {
#pragma unroll
            for (int p = 0; p < 16; ++p) {
                int st = s0 + p;
                float ur = buf[p].x, ui = buf[p].y;
                if (st + 16 < 64) buf[p] = U2[(size_t)(st+16)*STATE];
                float nr = fmaf(lre, h.x, fmaf(-lim, h.y, ur));
                float ni = fmaf(lre, h.y, fmaf( lim, h.x, ui));
                h.x = nr; h.y = ni;
                u16 a1,a2,a3, c1,c2,c3;
                split3(nr, a1,a2,a3);
                split3(ni, c1,c2,c3);
                size_t zo = zb + (size_t)st*NJ;
                ushort2 t2;
                t2.x = a1; t2.y = c1; *(ushort2*)(Z1 + zo) = t2;
                t2.x = a2; t2.y = c2; *(ushort2*)(Z2 + zo) = t2;
                t2.x = a3; t2.y = c3; *(ushort2*)(Z3 + zo) = t2;
            }
        }
        if (c == 7) HcOut[(size_t)b*STATE + n] = h;
    }
}

// ---------------- GEMM2 + last-block combine ----------
// grid (32 m-tiles, 4 n-tiles, z=4). 128x64 tile, nt=8 (K=256 per z).
// z 0..2: Z planes vs WC; z 3: X planes vs WD. 4th block per (m,n) combines.
struct G2P {
    const u16* Z[3]; const u16* X[3]; const u16* WC; const u16* WD;
    float* P; u16* O1; u16* O2; u16* O3; float* outp; int iter; int* cnt;
};

__global__ __launch_bounds__(256, 2)
void gemm2_k(G2P g) {
    __shared__ __align__(16) char smem[49152];   // 2 x 24KB (A dbuf)
    const int tid = threadIdx.x, lane = tid & 63, w = tid >> 6;
    const int wr = w & 1, wcq = w >> 1;
    const int m0 = blockIdx.x*128, n0 = blockIdx.y*64;
    const int z = blockIdx.z;
    const int hi5 = lane >> 5, lo5 = lane & 31;
    const int c32 = (n0 >> 5) + wcq;

    const u16* Ap[3]; const u16* Bp; int sA, kg0, t32b, NT32; size_t pBs;
    if (z < 3) {
        Ap[0]=g.Z[0]; Ap[1]=g.Z[1]; Ap[2]=g.Z[2];
        sA = NJ; kg0 = z*256; Bp = g.WC; pBs = PS_WC; t32b = z*8; NT32 = 24;
    } else {
        Ap[0]=g.X[0]; Ap[1]=g.X[1]; Ap[2]=g.X[2];
        sA = IN_CH; kg0 = 0; Bp = g.WD; pBs = PS_WD; t32b = 0; NT32 = 8;
    }

    f32x16 acc[2];
#pragma unroll
    for (int f = 0; f < 2; ++f)
#pragma unroll
        for (int i = 0; i < 16; ++i) acc[f][i] = 0.f;

    bf16x8 bwin[3][4][2];
    auto loadB = [&](int cw) {
#pragma unroll
        for (int p = 0; p < 3; ++p)
#pragma unroll
            for (int t = 0; t < 4; ++t)
#pragma unroll
                for (int h = 0; h < 2; ++h)
                    bwin[p][t][h] = *(const bf16x8*)(Bp + (size_t)p*pBs
                        + ((((size_t)(c32*NT32 + t32b + cw*4 + t)*2 + h)*2 + hi5) << 8)
                        + lo5*8);
    };

    auto stageA = [&](int ks, int buf) {
        int kg = kg0 + ks*32;
        char* L = smem + buf*24576;
#pragma unroll
        for (int r = 0; r < 6; ++r) {            // 1536 chunks of 16B
            int q = tid + r*256;
            int p = q >> 9, cq = q & 511, o = cq >> 7, row = cq & 127;
            gload_lds16(Ap[p] + (size_t)(m0 + row)*sA + kg + o*8,
                        L + (size_t)q*16);
        }
    };

    stageA(0, 0);
    loadB(0);
    __syncthreads();
    int cur = 0;
#pragma unroll
    for (int ks = 0; ks < 8; ++ks) {
        if (ks == 4) loadB(1);
        if (ks + 1 < 8) stageA(ks + 1, cur ^ 1);
        const char* L = smem + cur*24576;
        bf16x8 av[3][2][2];
#pragma unroll
        for (int p = 0; p < 3; ++p)
#pragma unroll
            for (int f = 0; f < 2; ++f)
#pragma unroll
                for (int h = 0; h < 2; ++h)
                    av[p][f][h] = *(const bf16x8*)(L + p*8192 + (2*h + hi5)*2048
                                                   + (wr*64 + f*32 + lo5)*16);
        const int tw = ks & 3;
#pragma unroll
        for (int t6 = 0; t6 < 6; ++t6)
#pragma unroll
            for (int f = 0; f < 2; ++f)
#pragma unroll
                for (int h = 0; h < 2; ++h)
                    acc[f] = __builtin_amdgcn_mfma_f32_32x32x16_bf16(
                        av[cPI[t6]][f][h], bwin[cPJ[t6]][tw][h], acc[f], 0, 0, 0);
        __syncthreads();
        cur ^= 1;
    }

    // epilogue: fp32 partial plane z
    {
        float* P = g.P + (size_t)z*M_ROWS*IN_CH;
#pragma unroll
        for (int f = 0; f < 2; ++f)
#pragma unroll
            for (int reg = 0; reg < 16; ++reg) {
                int row = m0 + wr*64 + f*32 + (reg & 3) + 8*(reg >> 2) + 4*hi5;
                int col = n0 + wcq*32 + lo5;
                P[(size_t)row*IN_CH + col] = acc[f][reg];
            }
    }

    // last-block ticket: 4th block for (m,n) combines
    __shared__ int s_old;
    __threadfence();
    __syncthreads();
    if (tid == 0) s_old = atomicAdd(&g.cnt[blockIdx.x*4 + blockIdx.y], 1);
    __syncthreads();
    if (s_old != 3) return;
    __threadfence();

    {
        const float* P0 = g.P;
#pragma unroll
        for (int kk = 0; kk < 8; ++kk) {
            int idx = tid + kk*256;              // 2048 float4 over 128x64
            int row = idx >> 4, c4 = idx & 15;
            size_t off = (size_t)(m0 + row)*IN_CH + n0 + c4*4;
            f32x4 v = *(const f32x4*)(P0 + off);
            v = v + *(const f32x4*)(P0 + (size_t)M_ROWS*IN_CH   + off);
            v = v + *(const f32x4*)(P0 + (size_t)2*M_ROWS*IN_CH + off);
            v = v + *(const f32x4*)(P0 + (size_t)3*M_ROWS*IN_CH + off);
            ushort4 o1, o2, o3;
            u16 a,b,c;
            split3(v[0],a,b,c); o1.x=a; o2.x=b; o3.x=c;
            split3(v[1],a,b,c); o1.y=a; o2.y=b; o3.y=c;
            split3(v[2],a,b,c); o1.z=a; o2.z=b; o3.z=c;
            split3(v[3],a,b,c); o1.w=a; o2.w=b; o3.w=c;
            *(ushort4*)(g.O1 + off) = o1;
            *(ushort4*)(g.O2 + off) = o2;
            *(ushort4*)(g.O3 + off) = o3;
            int grow = m0 + row;
            if ((grow & (SEQ-1)) == SEQ-1)
                *(float4*)&g.outp[(size_t)((grow >> 9)*OUT_SEQ + g.iter)*IN_CH
                                  + n0 + c4*4] = make_float4(v[0], v[1], v[2], v[3]);
        }
    }
}

// ---------------- launch ----------------
extern "C" void kernel_launch(void* const* d_in, const int* in_sizes, int n_in,
                              void* d_out, int out_size, void* d_ws, size_t ws_size,
                              hipStream_t stream) {
    const float* x_in      = (const float*)d_in[0];
    const float* nu_log    = (const float*)d_in[1];
    const float* theta_log = (const float*)d_in[2];
    const float* gamma_log = (const float*)d_in[3];
    const float* B_re      = (const float*)d_in[4];
    const float* B_im      = (const float*)d_in[5];
    const float* C_re      = (const float*)d_in[6];
    const float* C_im      = (const float*)d_in[7];
    const float* D         = (const float*)d_in[8];
    float* out = (float*)d_out;

    char* ws = (char*)d_ws;
    float* U   = (float*)(ws + B_U);
    u16* Z1 = (u16*)(ws + B_Z);
    u16* Z2 = Z1 + (size_t)M_ROWS*NJ;
    u16* Z3 = Z2 + (size_t)M_ROWS*NJ;
    u16* XA1 = (u16*)(ws + B_XA);
    u16* XA2 = XA1 + (size_t)M_ROWS*IN_CH;
    u16* XA3 = XA2 + (size_t)M_ROWS*IN_CH;
    u16* XB1 = (u16*)(ws + B_XB);
    u16* XB2 = XB1 + (size_t)M_ROWS*IN_CH;
    u16* XB3 = XB2 + (size_t)M_ROWS*IN_CH;
    u16* WB  = (u16*)(ws + B_WB);
    u16* WCt = (u16*)(ws + B_WC);
    u16* WDt = (u16*)(ws + B_WD);
    float* lam   = (float*)(ws + B_LAM);
    float* lam64 = lam + 768;
    float2* Hc0  = (float2*)(ws + B_HC);
    float2* Hc1  = Hc0 + (size_t)B_SZ*STATE;
    float2* carry = (float2*)(ws + B_CAR);
    int* cnt  = (int*)(ws + B_CNT);            // [32][96] then [32][128]
    int* cnt2 = cnt + OUT_SEQ*NCNT1;

    prep_lam_hc<<<1, 384, 0, stream>>>(nu_log, theta_log, lam, lam64, (float*)Hc0, cnt);
    prep_wb<<<PS_WB/256, 256, 0, stream>>>(B_re, B_im, gamma_log, WB);
    prep_wcd<<<(PS_WC + PS_WD)/256, 256, 0, stream>>>(C_re, C_im, D, WCt, WDt);
    prep_x<<<(M_ROWS*IN_CH)/256, 256, 0, stream>>>(x_in, XA1, XA2, XA3);

    for (int it = 0; it < OUT_SEQ; ++it) {
        u16* Xc[3]; u16* Xn[3];
        if (it & 1) { Xc[0]=XB1; Xc[1]=XB2; Xc[2]=XB3; Xn[0]=XA1; Xn[1]=XA2; Xn[2]=XA3; }
        else        { Xc[0]=XA1; Xc[1]=XA2; Xc[2]=XA3; Xn[0]=XB1; Xn[1]=XB2; Xn[2]=XB3; }
        float2* Hin  = (it & 1) ? Hc1 : Hc0;
        float2* Hout = (it & 1) ? Hc0 : Hc1;

        // GEMM1 + fused carries + last-block emit
        G1P g1;
        for (int p = 0; p < 3; ++p) g1.A[p] = Xc[p];
        gemm1_k<<<dim3(M_ROWS/64, NJ/64), 256, 0, stream>>>(
            g1, WB, U, lam, lam64, carry, Hin, Hout, Z1, Z2, Z3, cnt + it*NCNT1);

        // GEMM2 (z=4 split) + last-block combine
        G2P g2;
        g2.Z[0]=Z1; g2.Z[1]=Z2; g2.Z[2]=Z3;
        g2.X[0]=Xc[0]; g2.X[1]=Xc[1]; g2.X[2]=Xc[2];
        g2.WC = WCt; g2.WD = WDt; g2.P = U;
        g2.O1 = Xn[0]; g2.O2 = Xn[1]; g2.O3 = Xn[2];
        g2.outp = out; g2.iter = it; g2.cnt = cnt2 + it*NCNT2;
        gemm2_k<<<dim3(M_ROWS/128, IN_CH/64, 4), 256, 0, stream>>>(g2);
    }
}

// Round 10
// 1868.790 us; speedup vs baseline: 4.3818x; 4.3818x over previous
//
#include <hip/hip_runtime.h>
#include <hip/hip_bf16.h>
#include <math.h>

typedef unsigned short u16;
typedef __attribute__((ext_vector_type(8))) short bf16x8;
typedef __attribute__((ext_vector_type(4))) float f32x4;
typedef __attribute__((ext_vector_type(16))) float f32x16;

#define IN_CH   256
#define STATE   384
#define OUT_SEQ 32
#define B_SZ    8
#define SEQ     512
#define M_ROWS  4096
#define NJ      768   // 2*STATE

// plane sizes (elements)
#define PS_WB  (NJ*IN_CH)      // 196608
#define PS_WC  (IN_CH*NJ)      // 196608
#define PS_WD  (IN_CH*IN_CH)   // 65536

// ---------------- workspace layout (bytes) ----------------
static constexpr size_t B_U   = 0;                                   // U fp32
static constexpr size_t B_Z   = B_U  + 8*(size_t)M_ROWS*IN_CH*4;
static constexpr size_t B_XA  = B_Z  + 3*(size_t)M_ROWS*NJ*2;
static constexpr size_t B_XB  = B_XA + 3*(size_t)M_ROWS*IN_CH*2;
static constexpr size_t B_WB  = B_XB + 3*(size_t)M_ROWS*IN_CH*2;
static constexpr size_t B_WC  = B_WB + 3*(size_t)PS_WB*2;
static constexpr size_t B_WD  = B_WC + 3*(size_t)PS_WC*2;
static constexpr size_t B_LAM = B_WD + 3*(size_t)PS_WD*2;            // lam, lam64
static constexpr size_t B_HC  = B_LAM + 2*768*4;                     // Hc0, Hc1
static constexpr size_t B_CAR = B_HC  + 2*(size_t)B_SZ*NJ*4;         // carries

// ---------------- helpers ----------------
__device__ __forceinline__ u16 f2b(float v) {
    __hip_bfloat16 h = __float2bfloat16(v);
    return *(u16*)&h;
}
__device__ __forceinline__ float b2f(u16 u) {
    __hip_bfloat16 h = *(__hip_bfloat16*)&u;
    return __bfloat162float(h);
}
__device__ __forceinline__ void split3(float v, u16& a, u16& b, u16& c) {
    a = f2b(v);  float r1 = v  - b2f(a);
    b = f2b(r1); float r2 = r1 - b2f(b);
    c = f2b(r2);
}
__device__ __forceinline__ void gload_lds16(const void* g, void* l) {
    __builtin_amdgcn_global_load_lds(
        (const __attribute__((address_space(1))) void*)g,
        (__attribute__((address_space(3))) void*)l, 16, 0, 0);
}

// fragment-index decode: r (within one c32 block) -> (t32,h,hi5,lo5,e)
__device__ __forceinline__ void frag_decode(int r, int& t32, int& h, int& hi5,
                                            int& lo5, int& e) {
    t32 = r >> 10; int r2 = r & 1023;
    h = r2 >> 9;   int r3 = r2 & 511;
    hi5 = r3 >> 8; int r4 = r3 & 255;
    lo5 = r4 >> 3; e = r4 & 7;
}

// ---------------- prep kernels ----------------
__global__ void prep_lam_hc(const float* __restrict__ nu_log,
                            const float* __restrict__ th_log,
                            float* __restrict__ lam, float* __restrict__ lam64,
                            float* __restrict__ hc0) {
    int n = threadIdx.x;
    if (n < STATE) {
        float lm = expf(-expf(nu_log[n]));
        float th = expf(th_log[n]);
        float ar = lm * cosf(th), ai = lm * sinf(th);
        lam[2*n] = ar; lam[2*n+1] = ai;
        float pr = ar, pi = ai;
#pragma unroll
        for (int i = 0; i < 6; ++i) {   // lambda^64
            float nr = pr*pr - pi*pi, ni = 2.f*pr*pi;
            pr = nr; pi = ni;
        }
        lam64[2*n] = pr; lam64[2*n+1] = pi;
    }
    for (int i = threadIdx.x; i < B_SZ*NJ; i += blockDim.x) hc0[i] = 0.f;
}

// WB fragment-ordered: Ncols=768 (j), K=256. per-c32 block = 8192 elems, NT32=8.
__global__ void prep_wb(const float* __restrict__ B_re, const float* __restrict__ B_im,
                        const float* __restrict__ gamma_log, u16* __restrict__ W) {
    int idx = blockIdx.x*blockDim.x + threadIdx.x;   // < 196608
    int c32 = idx >> 13, r = idx & 8191;
    int t32,h,hi5,lo5,e; frag_decode(r, t32,h,hi5,lo5,e);
    int j = c32*32 + lo5;
    int k = t32*32 + (2*h + hi5)*8 + e;
    int n = j >> 1;
    float g = expf(gamma_log[n]);
    float v = g * ((j & 1) ? B_im[n*IN_CH + k] : B_re[n*IN_CH + k]);
    u16 a,b,cc; split3(v,a,b,cc);
    W[idx] = a; W[idx + PS_WB] = b; W[idx + 2*PS_WB] = cc;
}

// WC: Ncols=256 (o), K=768 (j): per-c32 block = 24576, NT32=24.
// WD: Ncols=256 (o), K=256 (c): per-c32 block = 8192,  NT32=8.
__global__ void prep_wcd(const float* __restrict__ C_re, const float* __restrict__ C_im,
                         const float* __restrict__ D,
                         u16* __restrict__ WC, u16* __restrict__ WD) {
    int idx = blockIdx.x*blockDim.x + threadIdx.x;   // < 196608 + 65536
    if (idx < PS_WC) {
        int c32 = idx / 24576, r = idx % 24576;
        int t32,h,hi5,lo5,e; frag_decode(r, t32,h,hi5,lo5,e);
        int o = c32*32 + lo5;
        int j = t32*32 + (2*h + hi5)*8 + e;
        int n = j >> 1;
        float v = (j & 1) ? -C_im[o*STATE + n] : C_re[o*STATE + n];
        u16 a,b,c; split3(v,a,b,c);
        WC[idx] = a; WC[idx + PS_WC] = b; WC[idx + 2*PS_WC] = c;
    } else {
        int q = idx - PS_WC;
        int c32 = q >> 13, r = q & 8191;
        int t32,h,hi5,lo5,e; frag_decode(r, t32,h,hi5,lo5,e);
        int o = c32*32 + lo5;
        int c = t32*32 + (2*h + hi5)*8 + e;
        float v = D[o*IN_CH + c];
        u16 a,b,cc; split3(v,a,b,cc);
        WD[q] = a; WD[q + PS_WD] = b; WD[q + 2*PS_WD] = cc;
    }
}

__global__ void prep_x(const float* __restrict__ x,
                       u16* __restrict__ X1, u16* __restrict__ X2, u16* __restrict__ X3) {
    int idx = blockIdx.x*blockDim.x + threadIdx.x;
    u16 a,b,c; split3(x[idx],a,b,c);
    X1[idx] = a; X2[idx] = b; X3[idx] = c;
}

// product order for bf16x3 (large terms first)
__device__ __constant__ const int cPI[6] = {0,0,1,0,1,2};
__device__ __constant__ const int cPJ[6] = {0,1,0,2,1,0};

// ---------------- GEMM1: U = sum_6 X_pi * WB_pj^T, + fused chunk-carry scan ----
// 64x64 tile, 4 waves (2x2), 32x32x16 MFMA, A-only LDS staging, B in regs
// (fragment-ordered coalesced loads).  [R7 structure — known good]
struct G1P { const u16* A[3]; };

__global__ __launch_bounds__(256, 2)
void gemm1_k(G1P ga, const u16* __restrict__ WBp, float* __restrict__ Uout,
             const float* __restrict__ lam, float2* __restrict__ carry) {
    __shared__ __align__(16) char smem[24576];   // 2 x 12KB (A dbuf)
    const int tid = threadIdx.x, lane = tid & 63, w = tid >> 6;
    const int wr = w & 1, wcq = w >> 1;
    const int m0 = blockIdx.x*64, n0 = blockIdx.y*64;
    const int hi5 = lane >> 5, lo5 = lane & 31;
    const int c32 = (n0 >> 5) + wcq;

    f32x16 acc;
#pragma unroll
    for (int i = 0; i < 16; ++i) acc[i] = 0.f;

    bf16x8 bwin[3][4][2];
    auto loadB = [&](int cw) {
#pragma unroll
        for (int p = 0; p < 3; ++p)
#pragma unroll
            for (int t = 0; t < 4; ++t)
#pragma unroll
                for (int h = 0; h < 2; ++h)
                    bwin[p][t][h] = *(const bf16x8*)(WBp + (size_t)p*PS_WB
                        + ((((size_t)(c32*8 + cw*4 + t)*2 + h)*2 + hi5) << 8) + lo5*8);
    };

    auto stageA = [&](int ks, int buf) {
        int kg = ks*32;
        char* L = smem + buf*12288;
#pragma unroll
        for (int r = 0; r < 3; ++r) {            // 768 chunks of 16B
            int q = tid + r*256;
            int p = q >> 8, cq = q & 255, o = cq >> 6, row = cq & 63;
            gload_lds16(ga.A[p] + (size_t)(m0 + row)*IN_CH + kg + o*8,
                        L + (size_t)q*16);
        }
    };

    stageA(0, 0);
    loadB(0);
    __syncthreads();
    int cur = 0;
#pragma unroll
    for (int ks = 0; ks < 8; ++ks) {
        if (ks == 4) loadB(1);
        if (ks + 1 < 8) stageA(ks + 1, cur ^ 1);
        const char* L = smem + cur*12288;
        bf16x8 av[3][2];
#pragma unroll
        for (int p = 0; p < 3; ++p)
#pragma unroll
            for (int h = 0; h < 2; ++h)
                av[p][h] = *(const bf16x8*)(L + p*4096 + (2*h + hi5)*1024
                                            + (wr*32 + lo5)*16);
        const int tw = ks & 3;
#pragma unroll
        for (int t6 = 0; t6 < 6; ++t6)
#pragma unroll
            for (int h = 0; h < 2; ++h)
                acc = __builtin_amdgcn_mfma_f32_32x32x16_bf16(
                    av[cPI[t6]][h], bwin[cPJ[t6]][tw][h], acc, 0, 0, 0);
        __syncthreads();
        cur ^= 1;
    }

    // epilogue: U to global + LDS tile; D layout col=lane&31, row=(reg&3)+8*(reg>>2)+4*hi5
    float* Ls = (float*)smem;                     // [64][64] fp32 = 16KB
#pragma unroll
    for (int reg = 0; reg < 16; ++reg) {
        int rl = wr*32 + (reg & 3) + 8*(reg >> 2) + 4*hi5;
        int cl = wcq*32 + lo5;
        float v = acc[reg];
        Uout[(size_t)(m0 + rl)*NJ + n0 + cl] = v;
        Ls[rl*64 + cl] = v;
    }
    __syncthreads();

    // fused chunk carry: 32 threads, 64-step local scan from LDS tile
    if (tid < 32) {
        int b = m0 >> 9, ch = (m0 >> 6) & 7;
        int n = (n0 >> 1) + tid;
        float lre = lam[2*n], lim = lam[2*n+1];
        float hr = 0.f, hm = 0.f;
        const float2* L2 = (const float2*)smem;   // [64][32] float2
        float2 pf[8];
#pragma unroll
        for (int p = 0; p < 8; ++p) pf[p] = L2[p*32 + tid];
        for (int s0 = 0; s0 < 64; s0 += 8) {
#pragma unroll
            for (int p = 0; p < 8; ++p) {
                int st = s0 + p;
                float ur = pf[p].x, ui = pf[p].y;
                if (st + 8 < 64) pf[p] = L2[(st + 8)*32 + tid];
                float nr = fmaf(lre, hr, fmaf(-lim, hm, ur));
                float nm = fmaf(lre, hm, fmaf( lim, hr, ui));
                hr = nr; hm = nm;
            }
        }
        carry[(size_t)(b*8 + ch)*STATE + n] = make_float2(hr, hm);
    }
}

// ---------------- scan emit: prefix from carries, emit Z splits ----------------
__global__ __launch_bounds__(64)
void scan_emit(const float* __restrict__ Uf,
               u16* __restrict__ Z1, u16* __restrict__ Z2, u16* __restrict__ Z3,
               const float* __restrict__ lam, const float* __restrict__ lam64,
               const float2* __restrict__ carry,
               const float2* __restrict__ HcIn, float2* __restrict__ HcOut) {
    int bx = blockIdx.x;
    int b = bx / 48, rem = bx % 48, g = rem >> 3, c = rem & 7;
    int n = g*64 + threadIdx.x;
    float lre = lam[2*n], lim = lam[2*n+1];
    float p64r = lam64[2*n], p64i = lam64[2*n+1];
    float2 h = HcIn[(size_t)b*STATE + n];
    for (int j = 0; j < c; ++j) {
        float2 cj = carry[(size_t)(b*8 + j)*STATE + n];
        float nr = fmaf(p64r, h.x, fmaf(-p64i, h.y, cj.x));
        float ni = fmaf(p64r, h.y, fmaf( p64i, h.x, cj.y));
        h.x = nr; h.y = ni;
    }
    const float2* U2 = (const float2*)Uf + ((size_t)(b*SEQ + c*64))*STATE + n;
    size_t zb = (size_t)(b*SEQ + c*64)*NJ + 2*n;
    float2 buf[16];
#pragma unroll
    for (int p = 0; p < 16; ++p) buf[p] = U2[(size_t)p*STATE];
    for (int s0 = 0; s0 < 64; s0 += 16) {
#pragma unroll
        for (int p = 0; p < 16; ++p) {
            int s = s0 + p;
            float ur = buf[p].x, ui = buf[p].y;
            if (s + 16 < 64) buf[p] = U2[(size_t)(s+16)*STATE];
            float nr = fmaf(lre, h.x, fmaf(-lim, h.y, ur));
            float ni = fmaf(lre, h.y, fmaf( lim, h.x, ui));
            h.x = nr; h.y = ni;
            u16 a1,a2,a3, c1,c2,c3;
            split3(nr, a1,a2,a3);
            split3(ni, c1,c2,c3);
            size_t zo = zb + (size_t)s*NJ;
            ushort2 t;
            t.x = a1; t.y = c1; *(ushort2*)(Z1 + zo) = t;
            t.x = a2; t.y = c2; *(ushort2*)(Z2 + zo) = t;
            t.x = a3; t.y = c3; *(ushort2*)(Z3 + zo) = t;
        }
    }
    if (c == 7) HcOut[(size_t)b*STATE + n] = h;
}

// ---------------- GEMM2: full-K (24 Z-steps + 8 X-steps), no partials ---------
// grid (64 m-tiles, 4 n-tiles). 64x64 tile, 4 waves, B in regs with 8 windows.
// Reload schedule (fixed R9 bug): at ks%4==2 reload next t0,1 BEFORE MFMAs
// (t0,1 dead); at ks%4==3 reload next t2,3 AFTER MFMAs (t3 just consumed).
struct G2P {
    const u16* Z[3]; const u16* X[3]; const u16* WC; const u16* WD;
    u16* O1; u16* O2; u16* O3; float* outp; int iter;
};

__global__ __launch_bounds__(256, 2)
void gemm2_k(G2P g) {
    __shared__ __align__(16) char smem[24576];   // 2 x 12KB (A dbuf)
    const int tid = threadIdx.x, lane = tid & 63, w = tid >> 6;
    const int wr = w & 1, wcq = w >> 1;
    const int m0 = blockIdx.x*64, n0 = blockIdx.y*64;
    const int hi5 = lane >> 5, lo5 = lane & 31;
    const int c32 = (n0 >> 5) + wcq;             // output col-32 group 0..7

    f32x16 acc;
#pragma unroll
    for (int i = 0; i < 16; ++i) acc[i] = 0.f;

    // B windows: wnd 0..5 from WC (t32 = wnd*4..), wnd 6..7 from WD
    bf16x8 bwin[3][4][2];
    auto loadB = [&](int wnd, int tlo, int thi) {
        const u16* Bp; size_t pBs; int base;
        if (wnd < 6) { Bp = g.WC; pBs = (size_t)PS_WC; base = c32*24 + wnd*4; }
        else         { Bp = g.WD; pBs = (size_t)PS_WD; base = c32*8 + (wnd - 6)*4; }
#pragma unroll
        for (int p = 0; p < 3; ++p)
#pragma unroll
            for (int t = tlo; t < thi; ++t)
#pragma unroll
                for (int h = 0; h < 2; ++h)
                    bwin[p][t][h] = *(const bf16x8*)(Bp + (size_t)p*pBs
                        + ((((size_t)(base + t)*2 + h)*2 + hi5) << 8) + lo5*8);
    };

    auto stageA = [&](int ks, int buf) {
        char* L = smem + buf*12288;
        const u16* const* Ap = (ks < 24) ? g.Z : g.X;
        const int sA = (ks < 24) ? NJ : IN_CH;
        const int kg = (ks < 24) ? ks*32 : (ks - 24)*32;
#pragma unroll
        for (int r = 0; r < 3; ++r) {            // 768 chunks of 16B
            int q = tid + r*256;
            int p = q >> 8, cq = q & 255, o = cq >> 6, row = cq & 63;
            gload_lds16(Ap[p] + (size_t)(m0 + row)*sA + kg + o*8,
                        L + (size_t)q*16);
        }
    };

    stageA(0, 0);
    loadB(0, 0, 4);
    __syncthreads();
    int cur = 0;
#pragma unroll
    for (int ks = 0; ks < 32; ++ks) {
        // next-window t0,1 reload: safe BEFORE MFMAs (this step uses t2, next t3)
        if ((ks & 3) == 2 && ks < 28) loadB((ks >> 2) + 1, 0, 2);
        if (ks + 1 < 32) stageA(ks + 1, cur ^ 1);
        const char* L = smem + cur*12288;
        bf16x8 av[3][2];
#pragma unroll
        for (int p = 0; p < 3; ++p)
#pragma unroll
            for (int h = 0; h < 2; ++h)
                av[p][h] = *(const bf16x8*)(L + p*4096 + (2*h + hi5)*1024
                                            + (wr*32 + lo5)*16);
        const int tw = ks & 3;
#pragma unroll
        for (int t6 = 0; t6 < 6; ++t6)
#pragma unroll
            for (int h = 0; h < 2; ++h)
                acc = __builtin_amdgcn_mfma_f32_32x32x16_bf16(
                    av[cPI[t6]][h], bwin[cPJ[t6]][tw][h], acc, 0, 0, 0);
        // next-window t2,3 reload: AFTER MFMAs (t3 of current window just used)
        if ((ks & 3) == 3 && ks < 28) loadB((ks >> 2) + 1, 2, 4);
        __syncthreads();
        cur ^= 1;
    }

    // epilogue: split3 -> Xn planes, plus out rows (last seq row of each batch)
#pragma unroll
    for (int reg = 0; reg < 16; ++reg) {
        int row = m0 + wr*32 + (reg & 3) + 8*(reg >> 2) + 4*hi5;
        int col = n0 + wcq*32 + lo5;
        float v = acc[reg];
        u16 a,b,c; split3(v, a,b,c);
        size_t off = (size_t)row*IN_CH + col;
        g.O1[off] = a; g.O2[off] = b; g.O3[off] = c;
        if ((row & (SEQ-1)) == SEQ-1)
            g.outp[(size_t)((row >> 9)*OUT_SEQ + g.iter)*IN_CH + col] = v;
    }
}

// ---------------- launch ----------------
extern "C" void kernel_launch(void* const* d_in, const int* in_sizes, int n_in,
                              void* d_out, int out_size, void* d_ws, size_t ws_size,
                              hipStream_t stream) {
    const float* x_in      = (const float*)d_in[0];
    const float* nu_log    = (const float*)d_in[1];
    const float* theta_log = (const float*)d_in[2];
    const float* gamma_log = (const float*)d_in[3];
    const float* B_re      = (const float*)d_in[4];
    const float* B_im      = (const float*)d_in[5];
    const float* C_re      = (const float*)d_in[6];
    const float* C_im      = (const float*)d_in[7];
    const float* D         = (const float*)d_in[8];
    float* out = (float*)d_out;

    char* ws = (char*)d_ws;
    float* U   = (float*)(ws + B_U);
    u16* Z1 = (u16*)(ws + B_Z);
    u16* Z2 = Z1 + (size_t)M_ROWS*NJ;
    u16* Z3 = Z2 + (size_t)M_ROWS*NJ;
    u16* XA1 = (u16*)(ws + B_XA);
    u16* XA2 = XA1 + (size_t)M_ROWS*IN_CH;
    u16* XA3 = XA2 + (size_t)M_ROWS*IN_CH;
    u16* XB1 = (u16*)(ws + B_XB);
    u16* XB2 = XB1 + (size_t)M_ROWS*IN_CH;
    u16* XB3 = XB2 + (size_t)M_ROWS*IN_CH;
    u16* WB  = (u16*)(ws + B_WB);
    u16* WCt = (u16*)(ws + B_WC);
    u16* WDt = (u16*)(ws + B_WD);
    float* lam   = (float*)(ws + B_LAM);
    float* lam64 = lam + 768;
    float2* Hc0  = (float2*)(ws + B_HC);
    float2* Hc1  = Hc0 + (size_t)B_SZ*STATE;
    float2* carry = (float2*)(ws + B_CAR);

    prep_lam_hc<<<1, 384, 0, stream>>>(nu_log, theta_log, lam, lam64, (float*)Hc0);
    prep_wb<<<PS_WB/256, 256, 0, stream>>>(B_re, B_im, gamma_log, WB);
    prep_wcd<<<(PS_WC + PS_WD)/256, 256, 0, stream>>>(C_re, C_im, D, WCt, WDt);
    prep_x<<<(M_ROWS*IN_CH)/256, 256, 0, stream>>>(x_in, XA1, XA2, XA3);

    for (int it = 0; it < OUT_SEQ; ++it) {
        u16* Xc[3]; u16* Xn[3];
        if (it & 1) { Xc[0]=XB1; Xc[1]=XB2; Xc[2]=XB3; Xn[0]=XA1; Xn[1]=XA2; Xn[2]=XA3; }
        else        { Xc[0]=XA1; Xc[1]=XA2; Xc[2]=XA3; Xn[0]=XB1; Xn[1]=XB2; Xn[2]=XB3; }
        float2* Hin  = (it & 1) ? Hc1 : Hc0;
        float2* Hout = (it & 1) ? Hc0 : Hc1;

        // GEMM1 + fused carries
        G1P g1;
        for (int p = 0; p < 3; ++p) g1.A[p] = Xc[p];
        gemm1_k<<<dim3(M_ROWS/64, NJ/64), 256, 0, stream>>>(g1, WB, U, lam, carry);

        // scan emit (prefix from carries)
        scan_emit<<<384, 64, 0, stream>>>(U, Z1, Z2, Z3, lam, lam64, carry, Hin, Hout);

        // GEMM2 full-K, epilogue writes Xn splits + out
        G2P g2;
        g2.Z[0]=Z1; g2.Z[1]=Z2; g2.Z[2]=Z3;
        g2.X[0]=Xc[0]; g2.X[1]=Xc[1]; g2.X[2]=Xc[2];
        g2.WC = WCt; g2.WD = WDt;
        g2.O1 = Xn[0]; g2.O2 = Xn[1]; g2.O3 = Xn[2];
        g2.outp = out; g2.iter = it;
        gemm2_k<<<dim3(M_ROWS/64, IN_CH/64), 256, 0, stream>>>(g2);
    }
}

// Round 11
// 1462.109 us; speedup vs baseline: 5.6006x; 1.2781x over previous
//
#include <hip/hip_runtime.h>
#include <hip/hip_bf16.h>
#include <math.h>

typedef unsigned short u16;
typedef __attribute__((ext_vector_type(8))) short bf16x8;
typedef __attribute__((ext_vector_type(4))) float f32x4;
typedef __attribute__((ext_vector_type(16))) float f32x16;

#define IN_CH   256
#define STATE   384
#define OUT_SEQ 32
#define B_SZ    8
#define SEQ     512
#define M_ROWS  4096
#define NJ      768   // 2*STATE

// plane sizes (elements)
#define PS_WB  (NJ*IN_CH)      // 196608
#define PS_WC  (IN_CH*NJ)      // 196608
#define PS_WD  (IN_CH*IN_CH)   // 65536
#define PS_Z   ((size_t)M_ROWS*NJ)
#define PS_X   ((size_t)M_ROWS*IN_CH)

// ---------------- workspace layout (bytes) ----------------
static constexpr size_t B_U   = 0;                                   // U fp32
static constexpr size_t B_Z   = B_U  + 8*(size_t)M_ROWS*IN_CH*4;
static constexpr size_t B_XA  = B_Z  + 3*(size_t)M_ROWS*NJ*2;
static constexpr size_t B_XB  = B_XA + 3*(size_t)M_ROWS*IN_CH*2;
static constexpr size_t B_WB  = B_XB + 3*(size_t)M_ROWS*IN_CH*2;
static constexpr size_t B_WC  = B_WB + 3*(size_t)PS_WB*2;
static constexpr size_t B_WD  = B_WC + 3*(size_t)PS_WC*2;
static constexpr size_t B_LAM = B_WD + 3*(size_t)PS_WD*2;            // lam, lam64
static constexpr size_t B_HC  = B_LAM + 2*768*4;                     // Hc0, Hc1
static constexpr size_t B_CAR = B_HC  + 2*(size_t)B_SZ*NJ*4;         // carries

// ---------------- helpers ----------------
__device__ __forceinline__ u16 f2b(float v) {
    __hip_bfloat16 h = __float2bfloat16(v);
    return *(u16*)&h;
}
__device__ __forceinline__ float b2f(u16 u) {
    __hip_bfloat16 h = *(__hip_bfloat16*)&u;
    return __bfloat162float(h);
}
__device__ __forceinline__ void split3(float v, u16& a, u16& b, u16& c) {
    a = f2b(v);  float r1 = v  - b2f(a);
    b = f2b(r1); float r2 = r1 - b2f(b);
    c = f2b(r2);
}

// A-fragment-ordered plane index: element (row, k), NKC = K/32 chunks.
// layout: [row>>5][k>>5][h=(k>>4)&1][hi5=(k>>3)&1][lo5=row&31][e=k&7]
__device__ __forceinline__ size_t a_idx(int row, int k, int NKC) {
    return ((size_t)(((row >> 5)*NKC + (k >> 5))*2 + ((k >> 4) & 1))*2 + ((k >> 3) & 1))*256
           + (size_t)(row & 31)*8 + (k & 7);
}

// fragment-index decode for weight prep: r -> (t32,h,hi5,lo5,e)
__device__ __forceinline__ void frag_decode(int r, int& t32, int& h, int& hi5,
                                            int& lo5, int& e) {
    t32 = r >> 10; int r2 = r & 1023;
    h = r2 >> 9;   int r3 = r2 & 511;
    hi5 = r3 >> 8; int r4 = r3 & 255;
    lo5 = r4 >> 3; e = r4 & 7;
}

// ---------------- prep kernels ----------------
__global__ void prep_lam_hc(const float* __restrict__ nu_log,
                            const float* __restrict__ th_log,
                            float* __restrict__ lam, float* __restrict__ lam64,
                            float* __restrict__ hc0) {
    int n = threadIdx.x;
    if (n < STATE) {
        float lm = expf(-expf(nu_log[n]));
        float th = expf(th_log[n]);
        float ar = lm * cosf(th), ai = lm * sinf(th);
        lam[2*n] = ar; lam[2*n+1] = ai;
        float pr = ar, pi = ai;
#pragma unroll
        for (int i = 0; i < 6; ++i) {   // lambda^64
            float nr = pr*pr - pi*pi, ni = 2.f*pr*pi;
            pr = nr; pi = ni;
        }
        lam64[2*n] = pr; lam64[2*n+1] = pi;
    }
    for (int i = threadIdx.x; i < B_SZ*NJ; i += blockDim.x) hc0[i] = 0.f;
}

// WB fragment-ordered: Ncols=768 (j), K=256. per-c32 block = 8192 elems, NT32=8.
__global__ void prep_wb(const float* __restrict__ B_re, const float* __restrict__ B_im,
                        const float* __restrict__ gamma_log, u16* __restrict__ W) {
    int idx = blockIdx.x*blockDim.x + threadIdx.x;   // < 196608
    int c32 = idx >> 13, r = idx & 8191;
    int t32,h,hi5,lo5,e; frag_decode(r, t32,h,hi5,lo5,e);
    int j = c32*32 + lo5;
    int k = t32*32 + (2*h + hi5)*8 + e;
    int n = j >> 1;
    float g = expf(gamma_log[n]);
    float v = g * ((j & 1) ? B_im[n*IN_CH + k] : B_re[n*IN_CH + k]);
    u16 a,b,cc; split3(v,a,b,cc);
    W[idx] = a; W[idx + PS_WB] = b; W[idx + 2*PS_WB] = cc;
}

// WC: Ncols=256 (o), K=768 (j): per-c32 block = 24576, NT32=24.
// WD: Ncols=256 (o), K=256 (c): per-c32 block = 8192,  NT32=8.
__global__ void prep_wcd(const float* __restrict__ C_re, const float* __restrict__ C_im,
                         const float* __restrict__ D,
                         u16* __restrict__ WC, u16* __restrict__ WD) {
    int idx = blockIdx.x*blockDim.x + threadIdx.x;   // < 196608 + 65536
    if (idx < PS_WC) {
        int c32 = idx / 24576, r = idx % 24576;
        int t32,h,hi5,lo5,e; frag_decode(r, t32,h,hi5,lo5,e);
        int o = c32*32 + lo5;
        int j = t32*32 + (2*h + hi5)*8 + e;
        int n = j >> 1;
        float v = (j & 1) ? -C_im[o*STATE + n] : C_re[o*STATE + n];
        u16 a,b,c; split3(v,a,b,c);
        WC[idx] = a; WC[idx + PS_WC] = b; WC[idx + 2*PS_WC] = c;
    } else {
        int q = idx - PS_WC;
        int c32 = q >> 13, r = q & 8191;
        int t32,h,hi5,lo5,e; frag_decode(r, t32,h,hi5,lo5,e);
        int o = c32*32 + lo5;
        int c = t32*32 + (2*h + hi5)*8 + e;
        float v = D[o*IN_CH + c];
        u16 a,b,cc; split3(v,a,b,cc);
        WD[q] = a; WD[q + PS_WD] = b; WD[q + 2*PS_WD] = cc;
    }
}

// X planes fragment-ordered (NKC=8)
__global__ void prep_x(const float* __restrict__ x,
                       u16* __restrict__ X1, u16* __restrict__ X2, u16* __restrict__ X3) {
    int idx = blockIdx.x*blockDim.x + threadIdx.x;   // < 4096*256
    int row = idx >> 8, k = idx & 255;
    u16 a,b,c; split3(x[idx],a,b,c);
    size_t o = a_idx(row, k, 8);
    X1[o] = a; X2[o] = b; X3[o] = c;
}

// product order for bf16x3 (large terms first)
__device__ __constant__ const int cPI[6] = {0,0,1,0,1,2};
__device__ __constant__ const int cPJ[6] = {0,1,0,2,1,0};

// ---------------- GEMM1: U = sum_6 X_pi * WB_pj^T + fused chunk-carry --------
// 64x64 tile, 4 waves (2x2), 32x32x16 MFMA. A and B both fragment-ordered
// global->reg loads; NO LDS staging, NO K-loop barriers. LDS only for the
// epilogue U tile + carry scan.
struct G1P { const u16* A[3]; };

__global__ __launch_bounds__(256, 2)
void gemm1_k(G1P ga, const u16* __restrict__ WBp, float* __restrict__ Uout,
             const float* __restrict__ lam, float2* __restrict__ carry) {
    __shared__ __align__(16) float Ls[64*64];    // 16KB, epilogue only
    const int tid = threadIdx.x, lane = tid & 63, w = tid >> 6;
    const int wr = w & 1, wcq = w >> 1;
    const int m0 = blockIdx.x*64, n0 = blockIdx.y*64;
    const int hi5 = lane >> 5, lo5 = lane & 31;
    const int c32 = (n0 >> 5) + wcq;
    const int m32 = blockIdx.x*2 + wr;

    f32x16 acc;
#pragma unroll
    for (int i = 0; i < 16; ++i) acc[i] = 0.f;

    bf16x8 bwin[3][4][2];
    auto loadB = [&](int cw, int tlo, int thi) {
#pragma unroll
        for (int p = 0; p < 3; ++p)
#pragma unroll
            for (int t = 0; t < 4; ++t) {
                if (t < tlo || t >= thi) continue;
#pragma unroll
                for (int h = 0; h < 2; ++h)
                    bwin[p][t][h] = *(const bf16x8*)(WBp + (size_t)p*PS_WB
                        + ((((size_t)(c32*8 + cw*4 + t)*2 + h)*2 + hi5) << 8) + lo5*8);
            }
    };
    bf16x8 av[2][3][2];
    auto loadA = [&](int buf, int ks) {
#pragma unroll
        for (int p = 0; p < 3; ++p)
#pragma unroll
            for (int h = 0; h < 2; ++h)
                av[buf][p][h] = *(const bf16x8*)(ga.A[p]
                    + ((((size_t)(m32*8 + ks)*2 + h)*2 + hi5) << 8) + lo5*8);
    };

    loadA(0, 0);
    loadB(0, 0, 4);
    loadA(1, 1);
#pragma unroll
    for (int ks = 0; ks < 8; ++ks) {
        if (ks == 2) loadB(1, 0, 2);            // win1 t0,1 (t0,1 of win0 dead)
        const int cb = ks & 1;
        const int tw = ks & 3;
#pragma unroll
        for (int t6 = 0; t6 < 6; ++t6)
#pragma unroll
            for (int h = 0; h < 2; ++h)
                acc = __builtin_amdgcn_mfma_f32_32x32x16_bf16(
                    av[cb][cPI[t6]][h], bwin[cPJ[t6]][tw][h], acc, 0, 0, 0);
        if (ks == 3) loadB(1, 2, 4);            // win1 t2,3 (t3 of win0 consumed)
        if (ks + 2 < 8) loadA(cb, ks + 2);
    }

    // epilogue: U to global + LDS tile; D layout col=lane&31, row=(reg&3)+8*(reg>>2)+4*hi5
#pragma unroll
    for (int reg = 0; reg < 16; ++reg) {
        int rl = wr*32 + (reg & 3) + 8*(reg >> 2) + 4*hi5;
        int cl = wcq*32 + lo5;
        float v = acc[reg];
        Uout[(size_t)(m0 + rl)*NJ + n0 + cl] = v;
        Ls[rl*64 + cl] = v;
    }
    __syncthreads();

    // fused chunk carry: 32 threads, 64-step local scan from LDS tile
    if (tid < 32) {
        int b = m0 >> 9, ch = (m0 >> 6) & 7;
        int n = (n0 >> 1) + tid;
        float lre = lam[2*n], lim = lam[2*n+1];
        float hr = 0.f, hm = 0.f;
        const float2* L2 = (const float2*)Ls;    // [64][32] float2
        float2 pf[8];
#pragma unroll
        for (int p = 0; p < 8; ++p) pf[p] = L2[p*32 + tid];
        for (int s0 = 0; s0 < 64; s0 += 8) {
#pragma unroll
            for (int p = 0; p < 8; ++p) {
                int st = s0 + p;
                float ur = pf[p].x, ui = pf[p].y;
                if (st + 8 < 64) pf[p] = L2[(st + 8)*32 + tid];
                float nr = fmaf(lre, hr, fmaf(-lim, hm, ur));
                float nm = fmaf(lre, hm, fmaf( lim, hr, ui));
                hr = nr; hm = nm;
            }
        }
        carry[(size_t)(b*8 + ch)*STATE + n] = make_float2(hr, hm);
    }
}

// ---------------- scan emit: prefix from carries, emit Z (fragment-ordered) ---
__global__ __launch_bounds__(64)
void scan_emit(const float* __restrict__ Uf,
               u16* __restrict__ Z1, u16* __restrict__ Z2, u16* __restrict__ Z3,
               const float* __restrict__ lam, const float* __restrict__ lam64,
               const float2* __restrict__ carry,
               const float2* __restrict__ HcIn, float2* __restrict__ HcOut) {
    int bx = blockIdx.x;
    int b = bx / 48, rem = bx % 48, g = rem >> 3, c = rem & 7;
    int n = g*64 + threadIdx.x;
    float lre = lam[2*n], lim = lam[2*n+1];
    float p64r = lam64[2*n], p64i = lam64[2*n+1];
    float2 h = HcIn[(size_t)b*STATE + n];
    for (int j = 0; j < c; ++j) {
        float2 cj = carry[(size_t)(b*8 + j)*STATE + n];
        float nr = fmaf(p64r, h.x, fmaf(-p64i, h.y, cj.x));
        float ni = fmaf(p64r, h.y, fmaf( p64i, h.x, cj.y));
        h.x = nr; h.y = ni;
    }
    const float2* U2 = (const float2*)Uf + ((size_t)(b*SEQ + c*64))*STATE + n;
    // fragment-order write base for j0 = 2n (j0&7 is even -> ushort2 fits)
    const int j0 = 2*n;
    const int jpart = ((j0 >> 5)*2 + ((j0 >> 4) & 1))*2 + ((j0 >> 3) & 1); // kc*4+h*2+hi
    const int e0 = j0 & 7;
    const int r32base = (b*SEQ + c*64) >> 5;     // two m32 groups: +0 (s<32), +1 (s>=32)
    float2 buf[16];
#pragma unroll
    for (int p = 0; p < 16; ++p) buf[p] = U2[(size_t)p*STATE];
    for (int s0 = 0; s0 < 64; s0 += 16) {
#pragma unroll
        for (int p = 0; p < 16; ++p) {
            int s = s0 + p;
            float ur = buf[p].x, ui = buf[p].y;
            if (s + 16 < 64) buf[p] = U2[(size_t)(s+16)*STATE];
            float nr = fmaf(lre, h.x, fmaf(-lim, h.y, ur));
            float ni = fmaf(lre, h.y, fmaf( lim, h.x, ui));
            h.x = nr; h.y = ni;
            u16 a1,a2,a3, c1,c2,c3;
            split3(nr, a1,a2,a3);
            split3(ni, c1,c2,c3);
            size_t zo = (((size_t)(r32base + (s >> 5))*96 + jpart) << 8)
                        + (size_t)(s & 31)*8 + e0;
            ushort2 t;
            t.x = a1; t.y = c1; *(ushort2*)(Z1 + zo) = t;
            t.x = a2; t.y = c2; *(ushort2*)(Z2 + zo) = t;
            t.x = a3; t.y = c3; *(ushort2*)(Z3 + zo) = t;
        }
    }
    if (c == 7) HcOut[(size_t)b*STATE + n] = h;
}

// ---------------- GEMM2: 8 waves, intra-block K-split (kg=0: chunks 0-15,
// kg=1: 16-31). A (Z frag-ordered / X frag-ordered) and B global->reg; no
// K-loop LDS/barriers. End: LDS reduction (16KB) + split3 epilogue + out.
struct G2P {
    const u16* Z[3]; const u16* X[3]; const u16* WC; const u16* WD;
    u16* O1; u16* O2; u16* O3; float* outp; int iter;
};

__global__ __launch_bounds__(512, 2)
void gemm2_k(G2P g) {
    __shared__ __align__(16) float Lred[64*64];  // 16KB
    const int tid = threadIdx.x, lane = tid & 63, w = tid >> 6;   // w 0..7
    const int kg = w >> 2, wq = w & 3;
    const int wr = wq & 1, wcq = wq >> 1;
    const int m0 = blockIdx.x*64, n0 = blockIdx.y*64;
    const int hi5 = lane >> 5, lo5 = lane & 31;
    const int c32 = (n0 >> 5) + wcq;
    const int m32 = blockIdx.x*2 + wr;
    const int cbase = kg*16;

    f32x16 acc;
#pragma unroll
    for (int i = 0; i < 16; ++i) acc[i] = 0.f;

    // chunk c (global 0..31): c<24 -> Z plane (NKC=24), else X plane (NKC=8)
    auto aptr = [&](int p, int c, int h) -> const u16* {
        if (c < 24)
            return g.Z[p] + ((((size_t)(m32*24 + c)*2 + h)*2 + hi5) << 8) + lo5*8;
        return g.X[p] + ((((size_t)(m32*8 + (c - 24))*2 + h)*2 + hi5) << 8) + lo5*8;
    };
    auto bptr = [&](int p, int c, int h) -> const u16* {
        if (c < 24)
            return g.WC + (size_t)p*PS_WC
                   + ((((size_t)(c32*24 + c)*2 + h)*2 + hi5) << 8) + lo5*8;
        return g.WD + (size_t)p*PS_WD
               + ((((size_t)(c32*8 + (c - 24))*2 + h)*2 + hi5) << 8) + lo5*8;
    };

    bf16x8 bwin[3][4][2];
    auto loadB = [&](int wnd, int tlo, int thi) {
#pragma unroll
        for (int p = 0; p < 3; ++p)
#pragma unroll
            for (int t = 0; t < 4; ++t) {
                if (t < tlo || t >= thi) continue;
#pragma unroll
                for (int h = 0; h < 2; ++h)
                    bwin[p][t][h] = *(const bf16x8*)bptr(p, cbase + wnd*4 + t, h);
            }
    };
    bf16x8 av[2][3][2];
    auto loadA = [&](int buf, int t) {
#pragma unroll
        for (int p = 0; p < 3; ++p)
#pragma unroll
            for (int h = 0; h < 2; ++h)
                av[buf][p][h] = *(const bf16x8*)aptr(p, cbase + t, h);
    };

    loadA(0, 0);
    loadB(0, 0, 4);
    loadA(1, 1);
#pragma unroll
    for (int t = 0; t < 16; ++t) {
        if ((t & 3) == 2 && t < 12) loadB((t >> 2) + 1, 0, 2);
        const int cb = t & 1;
        const int tw = t & 3;
#pragma unroll
        for (int t6 = 0; t6 < 6; ++t6)
#pragma unroll
            for (int h = 0; h < 2; ++h)
                acc = __builtin_amdgcn_mfma_f32_32x32x16_bf16(
                    av[cb][cPI[t6]][h], bwin[cPJ[t6]][tw][h], acc, 0, 0, 0);
        if ((t & 3) == 3 && t < 12) loadB((t >> 2) + 1, 2, 4);
        if (t + 2 < 16) loadA(cb, t + 2);
    }

    // kg=1 waves deposit partials; kg=0 waves sum + epilogue
    if (kg == 1) {
#pragma unroll
        for (int reg = 0; reg < 16; ++reg) {
            int rl = wr*32 + (reg & 3) + 8*(reg >> 2) + 4*hi5;
            int cl = wcq*32 + lo5;
            Lred[rl*64 + cl] = acc[reg];
        }
    }
    __syncthreads();
    if (kg == 0) {
#pragma unroll
        for (int reg = 0; reg < 16; ++reg) {
            int rl = wr*32 + (reg & 3) + 8*(reg >> 2) + 4*hi5;
            int cl = wcq*32 + lo5;
            float v = acc[reg] + Lred[rl*64 + cl];
            int row = m0 + rl, col = n0 + cl;
            u16 a,b,c; split3(v, a,b,c);
            size_t o = a_idx(row, col, 8);
            g.O1[o] = a; g.O2[o] = b; g.O3[o] = c;
            if ((row & (SEQ-1)) == SEQ-1)
                g.outp[(size_t)((row >> 9)*OUT_SEQ + g.iter)*IN_CH + col] = v;
        }
    }
}

// ---------------- launch ----------------
extern "C" void kernel_launch(void* const* d_in, const int* in_sizes, int n_in,
                              void* d_out, int out_size, void* d_ws, size_t ws_size,
                              hipStream_t stream) {
    const float* x_in      = (const float*)d_in[0];
    const float* nu_log    = (const float*)d_in[1];
    const float* theta_log = (const float*)d_in[2];
    const float* gamma_log = (const float*)d_in[3];
    const float* B_re      = (const float*)d_in[4];
    const float* B_im      = (const float*)d_in[5];
    const float* C_re      = (const float*)d_in[6];
    const float* C_im      = (const float*)d_in[7];
    const float* D         = (const float*)d_in[8];
    float* out = (float*)d_out;

    char* ws = (char*)d_ws;
    float* U   = (float*)(ws + B_U);
    u16* Z1 = (u16*)(ws + B_Z);
    u16* Z2 = Z1 + PS_Z;
    u16* Z3 = Z2 + PS_Z;
    u16* XA1 = (u16*)(ws + B_XA);
    u16* XA2 = XA1 + PS_X;
    u16* XA3 = XA2 + PS_X;
    u16* XB1 = (u16*)(ws + B_XB);
    u16* XB2 = XB1 + PS_X;
    u16* XB3 = XB2 + PS_X;
    u16* WB  = (u16*)(ws + B_WB);
    u16* WCt = (u16*)(ws + B_WC);
    u16* WDt = (u16*)(ws + B_WD);
    float* lam   = (float*)(ws + B_LAM);
    float* lam64 = lam + 768;
    float2* Hc0  = (float2*)(ws + B_HC);
    float2* Hc1  = Hc0 + (size_t)B_SZ*STATE;
    float2* carry = (float2*)(ws + B_CAR);

    prep_lam_hc<<<1, 384, 0, stream>>>(nu_log, theta_log, lam, lam64, (float*)Hc0);
    prep_wb<<<PS_WB/256, 256, 0, stream>>>(B_re, B_im, gamma_log, WB);
    prep_wcd<<<(PS_WC + PS_WD)/256, 256, 0, stream>>>(C_re, C_im, D, WCt, WDt);
    prep_x<<<(M_ROWS*IN_CH)/256, 256, 0, stream>>>(x_in, XA1, XA2, XA3);

    for (int it = 0; it < OUT_SEQ; ++it) {
        u16* Xc[3]; u16* Xn[3];
        if (it & 1) { Xc[0]=XB1; Xc[1]=XB2; Xc[2]=XB3; Xn[0]=XA1; Xn[1]=XA2; Xn[2]=XA3; }
        else        { Xc[0]=XA1; Xc[1]=XA2; Xc[2]=XA3; Xn[0]=XB1; Xn[1]=XB2; Xn[2]=XB3; }
        float2* Hin  = (it & 1) ? Hc1 : Hc0;
        float2* Hout = (it & 1) ? Hc0 : Hc1;

        // GEMM1 + fused carries
        G1P g1;
        for (int p = 0; p < 3; ++p) g1.A[p] = Xc[p];
        gemm1_k<<<dim3(M_ROWS/64, NJ/64), 256, 0, stream>>>(g1, WB, U, lam, carry);

        // scan emit (prefix from carries), Z fragment-ordered
        scan_emit<<<384, 64, 0, stream>>>(U, Z1, Z2, Z3, lam, lam64, carry, Hin, Hout);

        // GEMM2: 8-wave intra-block K-split, epilogue writes Xn frags + out
        G2P g2;
        g2.Z[0]=Z1; g2.Z[1]=Z2; g2.Z[2]=Z3;
        g2.X[0]=Xc[0]; g2.X[1]=Xc[1]; g2.X[2]=Xc[2];
        g2.WC = WCt; g2.WD = WDt;
        g2.O1 = Xn[0]; g2.O2 = Xn[1]; g2.O3 = Xn[2];
        g2.outp = out; g2.iter = it;
        gemm2_k<<<dim3(M_ROWS/64, IN_CH/64), 512, 0, stream>>>(g2);
    }
}

// Round 12
// 1332.418 us; speedup vs baseline: 6.1457x; 1.0973x over previous
//
#include <hip/hip_runtime.h>
#include <hip/hip_bf16.h>
#include <math.h>

typedef unsigned short u16;
typedef __attribute__((ext_vector_type(8))) short bf16x8;
typedef __attribute__((ext_vector_type(4))) float f32x4;

#define IN_CH   256
#define STATE   384
#define OUT_SEQ 32
#define B_SZ    8
#define SEQ     512
#define M_ROWS  4096
#define NJ      768   // 2*STATE

// plane sizes (elements)
#define PS_WB  (NJ*IN_CH)      // 196608
#define PS_WC  (IN_CH*NJ)      // 196608
#define PS_WD  (IN_CH*IN_CH)   // 65536
#define PS_Z   ((size_t)M_ROWS*NJ)
#define PS_X   ((size_t)M_ROWS*IN_CH)

// ---------------- workspace layout (bytes) ----------------
static constexpr size_t B_U   = 0;                                   // (unused now)
static constexpr size_t B_Z   = B_U  + 8*(size_t)M_ROWS*IN_CH*4;
static constexpr size_t B_XA  = B_Z  + 3*(size_t)M_ROWS*NJ*2;
static constexpr size_t B_XB  = B_XA + 3*(size_t)M_ROWS*IN_CH*2;
static constexpr size_t B_WB  = B_XB + 3*(size_t)M_ROWS*IN_CH*2;
static constexpr size_t B_WC  = B_WB + 3*(size_t)PS_WB*2;
static constexpr size_t B_WD  = B_WC + 3*(size_t)PS_WC*2;
static constexpr size_t B_LAM = B_WD + 3*(size_t)PS_WD*2;            // lam, lam32
static constexpr size_t B_HC  = B_LAM + 2*768*4;                     // Hc0, Hc1

// ---------------- helpers ----------------
__device__ __forceinline__ u16 f2b(float v) {
    __hip_bfloat16 h = __float2bfloat16(v);
    return *(u16*)&h;
}
__device__ __forceinline__ float b2f(u16 u) {
    __hip_bfloat16 h = *(__hip_bfloat16*)&u;
    return __bfloat162float(h);
}
__device__ __forceinline__ void split3(float v, u16& a, u16& b, u16& c) {
    a = f2b(v);  float r1 = v  - b2f(a);
    b = f2b(r1); float r2 = r1 - b2f(b);
    c = f2b(r2);
}

// A-fragment-ordered (32x32-family) plane index: element (row, k), NKC = K/32.
// layout: [row>>5][k>>5][h=(k>>4)&1][hi5=(k>>3)&1][lo5=row&31][e=k&7]
__device__ __forceinline__ size_t a_idx(int row, int k, int NKC) {
    return ((size_t)(((row >> 5)*NKC + (k >> 5))*2 + ((k >> 4) & 1))*2 + ((k >> 3) & 1))*256
           + (size_t)(row & 31)*8 + (k & 7);
}

// fragment-index decode for weight prep: r -> (t32,h,hi5,lo5,e)
__device__ __forceinline__ void frag_decode(int r, int& t32, int& h, int& hi5,
                                            int& lo5, int& e) {
    t32 = r >> 10; int r2 = r & 1023;
    h = r2 >> 9;   int r3 = r2 & 511;
    hi5 = r3 >> 8; int r4 = r3 & 255;
    lo5 = r4 >> 3; e = r4 & 7;
}

// ---------------- prep kernels ----------------
__global__ void prep_lam_hc(const float* __restrict__ nu_log,
                            const float* __restrict__ th_log,
                            float* __restrict__ lam, float* __restrict__ lam32,
                            float* __restrict__ hc0) {
    int n = threadIdx.x;
    if (n < STATE) {
        float lm = expf(-expf(nu_log[n]));
        float th = expf(th_log[n]);
        float ar = lm * cosf(th), ai = lm * sinf(th);
        lam[2*n] = ar; lam[2*n+1] = ai;
        float pr = ar, pi = ai;
#pragma unroll
        for (int i = 0; i < 5; ++i) {   // lambda^32
            float nr = pr*pr - pi*pi, ni = 2.f*pr*pi;
            pr = nr; pi = ni;
        }
        lam32[2*n] = pr; lam32[2*n+1] = pi;
    }
    for (int i = threadIdx.x; i < B_SZ*NJ; i += blockDim.x) hc0[i] = 0.f;
}

// WB fragment-ordered (32x32 family): Ncols=768 (j), K=256. NT32=8.
__global__ void prep_wb(const float* __restrict__ B_re, const float* __restrict__ B_im,
                        const float* __restrict__ gamma_log, u16* __restrict__ W) {
    int idx = blockIdx.x*blockDim.x + threadIdx.x;   // < 196608
    int c32 = idx >> 13, r = idx & 8191;
    int t32,h,hi5,lo5,e; frag_decode(r, t32,h,hi5,lo5,e);
    int j = c32*32 + lo5;
    int k = t32*32 + (2*h + hi5)*8 + e;
    int n = j >> 1;
    float g = expf(gamma_log[n]);
    float v = g * ((j & 1) ? B_im[n*IN_CH + k] : B_re[n*IN_CH + k]);
    u16 a,b,cc; split3(v,a,b,cc);
    W[idx] = a; W[idx + PS_WB] = b; W[idx + 2*PS_WB] = cc;
}

// WC: Ncols=256 (o), K=768 (j): per-c32 block = 24576, NT32=24.
// WD: Ncols=256 (o), K=256 (c): per-c32 block = 8192,  NT32=8.
__global__ void prep_wcd(const float* __restrict__ C_re, const float* __restrict__ C_im,
                         const float* __restrict__ D,
                         u16* __restrict__ WC, u16* __restrict__ WD) {
    int idx = blockIdx.x*blockDim.x + threadIdx.x;   // < 196608 + 65536
    if (idx < PS_WC) {
        int c32 = idx / 24576, r = idx % 24576;
        int t32,h,hi5,lo5,e; frag_decode(r, t32,h,hi5,lo5,e);
        int o = c32*32 + lo5;
        int j = t32*32 + (2*h + hi5)*8 + e;
        int n = j >> 1;
        float v = (j & 1) ? -C_im[o*STATE + n] : C_re[o*STATE + n];
        u16 a,b,c; split3(v,a,b,c);
        WC[idx] = a; WC[idx + PS_WC] = b; WC[idx + 2*PS_WC] = c;
    } else {
        int q = idx - PS_WC;
        int c32 = q >> 13, r = q & 8191;
        int t32,h,hi5,lo5,e; frag_decode(r, t32,h,hi5,lo5,e);
        int o = c32*32 + lo5;
        int c = t32*32 + (2*h + hi5)*8 + e;
        float v = D[o*IN_CH + c];
        u16 a,b,cc; split3(v,a,b,cc);
        WD[q] = a; WD[q + PS_WD] = b; WD[q + 2*PS_WD] = cc;
    }
}

// X planes fragment-ordered (NKC=8)
__global__ void prep_x(const float* __restrict__ x,
                       u16* __restrict__ X1, u16* __restrict__ X2, u16* __restrict__ X3) {
    int idx = blockIdx.x*blockDim.x + threadIdx.x;   // < 4096*256
    int row = idx >> 8, k = idx & 255;
    u16 a,b,c; split3(x[idx],a,b,c);
    size_t o = a_idx(row, k, 8);
    X1[o] = a; X2[o] = b; X3[o] = c;
}

// product order for bf16x3 (large terms first)
__device__ __constant__ const int cPI[6] = {0,0,1,0,1,2};
__device__ __constant__ const int cPJ[6] = {0,1,0,2,1,0};

// ---------------- FRONT: U = sum_6 X_pi*WB_pj^T (M=512,N=32,K=256) in LDS,
// then chunked scan (16 states x 32 chunks of 16 steps) + split3 Z emit.
// grid (8 b, 24 jt). 512 threads (8 waves). 16x16x32 MFMA.
// A-frag (16x16x32): row=lane&15, k=(lane>>4)*8+e ; B same with col=lane&15.
// D: col=lane&15, row=(lane>>4)*4+reg.
struct G1P { const u16* A[3]; };

__global__ __launch_bounds__(512, 4)
void front_k(G1P ga, const u16* __restrict__ WBp,
             u16* __restrict__ Z1, u16* __restrict__ Z2, u16* __restrict__ Z3,
             const float* __restrict__ lam, const float* __restrict__ lam32,
             const float2* __restrict__ HcIn, float2* __restrict__ HcOut) {
    __shared__ __align__(16) float Ls[512*33];     // 67.6KB U tile, pad 33
    __shared__ float2 car[32][16];                  // [ch][st]
    __shared__ float2 hp[32][16];
    const int tid = threadIdx.x, lane = tid & 63, w = tid >> 6;
    const int b = blockIdx.x, jt = blockIdx.y;
    const int l15 = lane & 15, q = lane >> 4;
    const int hb = q >> 1, hi5q = q & 1;

    f32x4 acc[4][2];
#pragma unroll
    for (int i = 0; i < 4; ++i)
#pragma unroll
        for (int n16 = 0; n16 < 2; ++n16) acc[i][n16] = 0.f;

#pragma unroll
    for (int kc = 0; kc < 8; ++kc) {
        bf16x8 av[4][3], bv[2][3];
#pragma unroll
        for (int p = 0; p < 3; ++p) {
#pragma unroll
            for (int i = 0; i < 4; ++i) {
                int m16 = i*8 + w;
                int row32 = b*16 + (m16 >> 1);
                int rin = ((m16 & 1) << 4) + l15;
                av[i][p] = *(const bf16x8*)(ga.A[p]
                    + ((((size_t)(row32*8 + kc)*2 + hb)*2 + hi5q) << 8) + rin*8);
            }
#pragma unroll
            for (int n16 = 0; n16 < 2; ++n16)
                bv[n16][p] = *(const bf16x8*)(WBp + (size_t)p*PS_WB
                    + ((((size_t)(jt*8 + kc)*2 + hb)*2 + hi5q) << 8) + (n16*16 + l15)*8);
        }
#pragma unroll
        for (int t6 = 0; t6 < 6; ++t6)
#pragma unroll
            for (int i = 0; i < 4; ++i)
#pragma unroll
                for (int n16 = 0; n16 < 2; ++n16)
                    acc[i][n16] = __builtin_amdgcn_mfma_f32_16x16x32_bf16(
                        av[i][cPI[t6]], bv[n16][cPJ[t6]], acc[i][n16], 0, 0, 0);
    }

    // deposit U tile to LDS
#pragma unroll
    for (int i = 0; i < 4; ++i) {
        int m16 = i*8 + w;
#pragma unroll
        for (int n16 = 0; n16 < 2; ++n16)
#pragma unroll
            for (int r = 0; r < 4; ++r) {
                int s = m16*16 + q*4 + r;
                int jl = n16*16 + l15;
                Ls[s*33 + jl] = acc[i][n16][r];
            }
    }
    __syncthreads();

    // pass 1: chunk-local carries. 256 threads: st = tid&15, ch = tid>>4 (0..15)
    // chunks of 32 steps -> 16 chunks... (use 16 chunks x 32 steps)
    if (tid < 256) {
        int st = tid & 15, ch = tid >> 4;        // ch 0..15, 32 steps each
        int n = jt*16 + st;
        float lre = lam[2*n], lim = lam[2*n+1];
        float hr = 0.f, hm = 0.f;
        for (int t = 0; t < 32; ++t) {
            int s = ch*32 + t;
            float ur = Ls[s*33 + 2*st], ui = Ls[s*33 + 2*st + 1];
            float nr = fmaf(lre, hr, fmaf(-lim, hm, ur));
            float nm = fmaf(lre, hm, fmaf( lim, hr, ui));
            hr = nr; hm = nm;
        }
        car[ch][st] = make_float2(hr, hm);
    }
    __syncthreads();

    // prefix: 16 threads, chain over 16 chunks with lambda^32
    if (tid < 16) {
        int st = tid, n = jt*16 + st;
        float l32r = lam32[2*n], l32i = lam32[2*n+1];
        float2 hh = HcIn[(size_t)b*STATE + n];
        hp[0][st] = hh;
        for (int ch = 1; ch < 16; ++ch) {
            float2 cj = car[ch-1][st];
            float nr = fmaf(l32r, hh.x, fmaf(-l32i, hh.y, cj.x));
            float ni = fmaf(l32r, hh.y, fmaf( l32i, hh.x, cj.y));
            hh.x = nr; hh.y = ni;
            hp[ch][st] = hh;
        }
    }
    __syncthreads();

    // pass 2: re-run recurrence from prefix, split3, emit Z frag-ordered
    if (tid < 256) {
        int st = tid & 15, ch = tid >> 4;
        int n = jt*16 + st;
        float lre = lam[2*n], lim = lam[2*n+1];
        float2 hh = hp[ch][st];
        int j0 = jt*32 + 2*st;
        for (int t = 0; t < 32; ++t) {
            int s = ch*32 + t;
            float ur = Ls[s*33 + 2*st], ui = Ls[s*33 + 2*st + 1];
            float nr = fmaf(lre, hh.x, fmaf(-lim, hh.y, ur));
            float ni = fmaf(lre, hh.y, fmaf( lim, hh.x, ui));
            hh.x = nr; hh.y = ni;
            u16 a1,a2,a3, c1,c2,c3;
            split3(nr, a1,a2,a3);
            split3(ni, c1,c2,c3);
            size_t zo = a_idx(b*512 + s, j0, 24);
            ushort2 t2;
            t2.x = a1; t2.y = c1; *(ushort2*)(Z1 + zo) = t2;
            t2.x = a2; t2.y = c2; *(ushort2*)(Z2 + zo) = t2;
            t2.x = a3; t2.y = c3; *(ushort2*)(Z3 + zo) = t2;
        }
        if (ch == 15) HcOut[(size_t)b*STATE + n] = hh;
    }
}

// ---------------- GEMM2: 8 waves, intra-block K-split (kg=0: chunks 0-15,
// kg=1: 16-31). A (Z/X frag-ordered) and B global->reg; no K-loop barriers.
// End: LDS reduction + split3 epilogue + out.   [R11 — known good]
struct G2P {
    const u16* Z[3]; const u16* X[3]; const u16* WC; const u16* WD;
    u16* O1; u16* O2; u16* O3; float* outp; int iter;
};

__global__ __launch_bounds__(512, 2)
void gemm2_k(G2P g) {
    __shared__ __align__(16) float Lred[64*64];  // 16KB
    const int tid = threadIdx.x, lane = tid & 63, w = tid >> 6;   // w 0..7
    const int kg = w >> 2, wq = w & 3;
    const int wr = wq & 1, wcq = wq >> 1;
    const int m0 = blockIdx.x*64, n0 = blockIdx.y*64;
    const int hi5 = lane >> 5, lo5 = lane & 31;
    const int c32 = (n0 >> 5) + wcq;
    const int m32 = blockIdx.x*2 + wr;
    const int cbase = kg*16;

    f32x4 acc4[4];
    float acc[16];
#pragma unroll
    for (int i = 0; i < 16; ++i) acc[i] = 0.f;
    typedef __attribute__((ext_vector_type(16))) float f32x16_t;
    f32x16_t accv;
#pragma unroll
    for (int i = 0; i < 16; ++i) accv[i] = 0.f;
    (void)acc4; (void)acc;

    auto aptr = [&](int p, int c, int h) -> const u16* {
        if (c < 24)
            return g.Z[p] + ((((size_t)(m32*24 + c)*2 + h)*2 + hi5) << 8) + lo5*8;
        return g.X[p] + ((((size_t)(m32*8 + (c - 24))*2 + h)*2 + hi5) << 8) + lo5*8;
    };
    auto bptr = [&](int p, int c, int h) -> const u16* {
        if (c < 24)
            return g.WC + (size_t)p*PS_WC
                   + ((((size_t)(c32*24 + c)*2 + h)*2 + hi5) << 8) + lo5*8;
        return g.WD + (size_t)p*PS_WD
               + ((((size_t)(c32*8 + (c - 24))*2 + h)*2 + hi5) << 8) + lo5*8;
    };

    bf16x8 bwin[3][4][2];
    auto loadB = [&](int wnd, int tlo, int thi) {
#pragma unroll
        for (int p = 0; p < 3; ++p)
#pragma unroll
            for (int t = 0; t < 4; ++t) {
                if (t < tlo || t >= thi) continue;
#pragma unroll
                for (int h = 0; h < 2; ++h)
                    bwin[p][t][h] = *(const bf16x8*)bptr(p, cbase + wnd*4 + t, h);
            }
    };
    bf16x8 av[2][3][2];
    auto loadA = [&](int buf, int t) {
#pragma unroll
        for (int p = 0; p < 3; ++p)
#pragma unroll
            for (int h = 0; h < 2; ++h)
                av[buf][p][h] = *(const bf16x8*)aptr(p, cbase + t, h);
    };

    loadA(0, 0);
    loadB(0, 0, 4);
    loadA(1, 1);
#pragma unroll
    for (int t = 0; t < 16; ++t) {
        if ((t & 3) == 2 && t < 12) loadB((t >> 2) + 1, 0, 2);
        const int cb = t & 1;
        const int tw = t & 3;
#pragma unroll
        for (int t6 = 0; t6 < 6; ++t6)
            accv = __builtin_amdgcn_mfma_f32_32x32x16_bf16(
                av[cb][cPI[t6]][0], bwin[cPJ[t6]][tw][0],
                __builtin_amdgcn_mfma_f32_32x32x16_bf16(
                    av[cb][cPI[t6]][1], bwin[cPJ[t6]][tw][1], accv, 0, 0, 0),
                0, 0, 0);
        if ((t & 3) == 3 && t < 12) loadB((t >> 2) + 1, 2, 4);
        if (t + 2 < 16) loadA(cb, t + 2);
    }

    // kg=1 waves deposit partials; kg=0 waves sum + epilogue
    if (kg == 1) {
#pragma unroll
        for (int reg = 0; reg < 16; ++reg) {
            int rl = wr*32 + (reg & 3) + 8*(reg >> 2) + 4*hi5;
            int cl = wcq*32 + lo5;
            Lred[rl*64 + cl] = accv[reg];
        }
    }
    __syncthreads();
    if (kg == 0) {
#pragma unroll
        for (int reg = 0; reg < 16; ++reg) {
            int rl = wr*32 + (reg & 3) + 8*(reg >> 2) + 4*hi5;
            int cl = wcq*32 + lo5;
            float v = accv[reg] + Lred[rl*64 + cl];
            int row = m0 + rl, col = n0 + cl;
            u16 a,b,c; split3(v, a,b,c);
            size_t o = a_idx(row, col, 8);
            g.O1[o] = a; g.O2[o] = b; g.O3[o] = c;
            if ((row & (SEQ-1)) == SEQ-1)
                g.outp[(size_t)((row >> 9)*OUT_SEQ + g.iter)*IN_CH + col] = v;
        }
    }
}

// ---------------- launch ----------------
extern "C" void kernel_launch(void* const* d_in, const int* in_sizes, int n_in,
                              void* d_out, int out_size, void* d_ws, size_t ws_size,
                              hipStream_t stream) {
    const float* x_in      = (const float*)d_in[0];
    const float* nu_log    = (const float*)d_in[1];
    const float* theta_log = (const float*)d_in[2];
    const float* gamma_log = (const float*)d_in[3];
    const float* B_re      = (const float*)d_in[4];
    const float* B_im      = (const float*)d_in[5];
    const float* C_re      = (const float*)d_in[6];
    const float* C_im      = (const float*)d_in[7];
    const float* D         = (const float*)d_in[8];
    float* out = (float*)d_out;

    char* ws = (char*)d_ws;
    u16* Z1 = (u16*)(ws + B_Z);
    u16* Z2 = Z1 + PS_Z;
    u16* Z3 = Z2 + PS_Z;
    u16* XA1 = (u16*)(ws + B_XA);
    u16* XA2 = XA1 + PS_X;
    u16* XA3 = XA2 + PS_X;
    u16* XB1 = (u16*)(ws + B_XB);
    u16* XB2 = XB1 + PS_X;
    u16* XB3 = XB2 + PS_X;
    u16* WB  = (u16*)(ws + B_WB);
    u16* WCt = (u16*)(ws + B_WC);
    u16* WDt = (u16*)(ws + B_WD);
    float* lam   = (float*)(ws + B_LAM);
    float* lam32 = lam + 768;
    float2* Hc0  = (float2*)(ws + B_HC);
    float2* Hc1  = Hc0 + (size_t)B_SZ*STATE;

    prep_lam_hc<<<1, 384, 0, stream>>>(nu_log, theta_log, lam, lam32, (float*)Hc0);
    prep_wb<<<PS_WB/256, 256, 0, stream>>>(B_re, B_im, gamma_log, WB);
    prep_wcd<<<(PS_WC + PS_WD)/256, 256, 0, stream>>>(C_re, C_im, D, WCt, WDt);
    prep_x<<<(M_ROWS*IN_CH)/256, 256, 0, stream>>>(x_in, XA1, XA2, XA3);

    for (int it = 0; it < OUT_SEQ; ++it) {
        u16* Xc[3]; u16* Xn[3];
        if (it & 1) { Xc[0]=XB1; Xc[1]=XB2; Xc[2]=XB3; Xn[0]=XA1; Xn[1]=XA2; Xn[2]=XA3; }
        else        { Xc[0]=XA1; Xc[1]=XA2; Xc[2]=XA3; Xn[0]=XB1; Xn[1]=XB2; Xn[2]=XB3; }
        float2* Hin  = (it & 1) ? Hc1 : Hc0;
        float2* Hout = (it & 1) ? Hc0 : Hc1;

        // FRONT: gemm1 (LDS U) + scan + Z emit + HcOut
        G1P g1;
        for (int p = 0; p < 3; ++p) g1.A[p] = Xc[p];
        front_k<<<dim3(B_SZ, 24), 512, 0, stream>>>(
            g1, WB, Z1, Z2, Z3, lam, lam32, Hin, Hout);

        // GEMM2: 8-wave intra-block K-split, epilogue writes Xn frags + out
        G2P g2;
        g2.Z[0]=Z1; g2.Z[1]=Z2; g2.Z[2]=Z3;
        g2.X[0]=Xc[0]; g2.X[1]=Xc[1]; g2.X[2]=Xc[2];
        g2.WC = WCt; g2.WD = WDt;
        g2.O1 = Xn[0]; g2.O2 = Xn[1]; g2.O3 = Xn[2];
        g2.outp = out; g2.iter = it;
        gemm2_k<<<dim3(M_ROWS/64, IN_CH/64), 512, 0, stream>>>(g2);
    }
}

// Round 13
// 1330.352 us; speedup vs baseline: 6.1552x; 1.0016x over previous
//
#include <hip/hip_runtime.h>
#include <hip/hip_bf16.h>
#include <math.h>

typedef unsigned short u16;
typedef __attribute__((ext_vector_type(8))) short bf16x8;
typedef __attribute__((ext_vector_type(4))) float f32x4;

#define IN_CH   256
#define STATE   384
#define OUT_SEQ 32
#define B_SZ    8
#define SEQ     512
#define M_ROWS  4096
#define NJ      768   // 2*STATE

// plane sizes (elements)
#define PS_WB  (NJ*IN_CH)      // 196608
#define PS_WC  (IN_CH*NJ)      // 196608
#define PS_WD  (IN_CH*IN_CH)   // 65536
#define PS_Z   ((size_t)M_ROWS*NJ)
#define PS_X   ((size_t)M_ROWS*IN_CH)

// ---------------- workspace layout (bytes) ----------------
static constexpr size_t B_U   = 0;                                   // (unused)
static constexpr size_t B_Z   = B_U  + 8*(size_t)M_ROWS*IN_CH*4;
static constexpr size_t B_XA  = B_Z  + 3*(size_t)M_ROWS*NJ*2;
static constexpr size_t B_XB  = B_XA + 3*(size_t)M_ROWS*IN_CH*2;
static constexpr size_t B_WB  = B_XB + 3*(size_t)M_ROWS*IN_CH*2;
static constexpr size_t B_WC  = B_WB + 3*(size_t)PS_WB*2;
static constexpr size_t B_WD  = B_WC + 3*(size_t)PS_WC*2;
static constexpr size_t B_LAM = B_WD + 3*(size_t)PS_WD*2;            // lam, lam16
static constexpr size_t B_HC  = B_LAM + 2*768*4;                     // Hc0, Hc1

// ---------------- helpers ----------------
__device__ __forceinline__ u16 f2b(float v) {
    __hip_bfloat16 h = __float2bfloat16(v);
    return *(u16*)&h;
}
__device__ __forceinline__ float b2f(u16 u) {
    __hip_bfloat16 h = *(__hip_bfloat16*)&u;
    return __bfloat162float(h);
}
__device__ __forceinline__ void split3(float v, u16& a, u16& b, u16& c) {
    a = f2b(v);  float r1 = v  - b2f(a);
    b = f2b(r1); float r2 = r1 - b2f(b);
    c = f2b(r2);
}

// A-fragment-ordered (32x32-family) plane index: element (row, k), NKC = K/32.
// layout: [row>>5][k>>5][h=(k>>4)&1][hi5=(k>>3)&1][lo5=row&31][e=k&7]
__device__ __forceinline__ size_t a_idx(int row, int k, int NKC) {
    return ((size_t)(((row >> 5)*NKC + (k >> 5))*2 + ((k >> 4) & 1))*2 + ((k >> 3) & 1))*256
           + (size_t)(row & 31)*8 + (k & 7);
}

// fragment-index decode for weight prep: r -> (t32,h,hi5,lo5,e)
__device__ __forceinline__ void frag_decode(int r, int& t32, int& h, int& hi5,
                                            int& lo5, int& e) {
    t32 = r >> 10; int r2 = r & 1023;
    h = r2 >> 9;   int r3 = r2 & 511;
    hi5 = r3 >> 8; int r4 = r3 & 255;
    lo5 = r4 >> 3; e = r4 & 7;
}

// ---------------- prep kernels ----------------
__global__ void prep_lam_hc(const float* __restrict__ nu_log,
                            const float* __restrict__ th_log,
                            float* __restrict__ lam, float* __restrict__ lam16,
                            float* __restrict__ hc0) {
    int n = threadIdx.x;
    if (n < STATE) {
        float lm = expf(-expf(nu_log[n]));
        float th = expf(th_log[n]);
        float ar = lm * cosf(th), ai = lm * sinf(th);
        lam[2*n] = ar; lam[2*n+1] = ai;
        float pr = ar, pi = ai;
#pragma unroll
        for (int i = 0; i < 4; ++i) {   // lambda^16
            float nr = pr*pr - pi*pi, ni = 2.f*pr*pi;
            pr = nr; pi = ni;
        }
        lam16[2*n] = pr; lam16[2*n+1] = pi;
    }
    for (int i = threadIdx.x; i < B_SZ*NJ; i += blockDim.x) hc0[i] = 0.f;
}

// WB fragment-ordered (32x32 family): Ncols=768 (j), K=256. NT32=8.
__global__ void prep_wb(const float* __restrict__ B_re, const float* __restrict__ B_im,
                        const float* __restrict__ gamma_log, u16* __restrict__ W) {
    int idx = blockIdx.x*blockDim.x + threadIdx.x;   // < 196608
    int c32 = idx >> 13, r = idx & 8191;
    int t32,h,hi5,lo5,e; frag_decode(r, t32,h,hi5,lo5,e);
    int j = c32*32 + lo5;
    int k = t32*32 + (2*h + hi5)*8 + e;
    int n = j >> 1;
    float g = expf(gamma_log[n]);
    float v = g * ((j & 1) ? B_im[n*IN_CH + k] : B_re[n*IN_CH + k]);
    u16 a,b,cc; split3(v,a,b,cc);
    W[idx] = a; W[idx + PS_WB] = b; W[idx + 2*PS_WB] = cc;
}

// WC: Ncols=256 (o), K=768 (j): per-c32 block = 24576, NT32=24.
// WD: Ncols=256 (o), K=256 (c): per-c32 block = 8192,  NT32=8.
__global__ void prep_wcd(const float* __restrict__ C_re, const float* __restrict__ C_im,
                         const float* __restrict__ D,
                         u16* __restrict__ WC, u16* __restrict__ WD) {
    int idx = blockIdx.x*blockDim.x + threadIdx.x;   // < 196608 + 65536
    if (idx < PS_WC) {
        int c32 = idx / 24576, r = idx % 24576;
        int t32,h,hi5,lo5,e; frag_decode(r, t32,h,hi5,lo5,e);
        int o = c32*32 + lo5;
        int j = t32*32 + (2*h + hi5)*8 + e;
        int n = j >> 1;
        float v = (j & 1) ? -C_im[o*STATE + n] : C_re[o*STATE + n];
        u16 a,b,c; split3(v,a,b,c);
        WC[idx] = a; WC[idx + PS_WC] = b; WC[idx + 2*PS_WC] = c;
    } else {
        int q = idx - PS_WC;
        int c32 = q >> 13, r = q & 8191;
        int t32,h,hi5,lo5,e; frag_decode(r, t32,h,hi5,lo5,e);
        int o = c32*32 + lo5;
        int c = t32*32 + (2*h + hi5)*8 + e;
        float v = D[o*IN_CH + c];
        u16 a,b,cc; split3(v,a,b,cc);
        WD[q] = a; WD[q + PS_WD] = b; WD[q + 2*PS_WD] = cc;
    }
}

// X planes fragment-ordered (NKC=8)
__global__ void prep_x(const float* __restrict__ x,
                       u16* __restrict__ X1, u16* __restrict__ X2, u16* __restrict__ X3) {
    int idx = blockIdx.x*blockDim.x + threadIdx.x;   // < 4096*256
    int row = idx >> 8, k = idx & 255;
    u16 a,b,c; split3(x[idx],a,b,c);
    size_t o = a_idx(row, k, 8);
    X1[o] = a; X2[o] = b; X3[o] = c;
}

// product order for bf16x3 (large terms first)
__device__ __constant__ const int cPI[6] = {0,0,1,0,1,2};
__device__ __constant__ const int cPJ[6] = {0,1,0,2,1,0};

// ---------------- FRONT: U = sum_6 X_pi*WB_pj^T (M=512,N=32,K=256) in LDS,
// then chunked scan (16 states x 32 chunks of 16 steps) + split3 Z emit.
// 1-D grid 192, XCD-swizzled: b = bid&7, jt = bid>>3. 512 threads (8 waves).
// 16x16x32 MFMA with 2-deep explicit prefetch.
struct G1P { const u16* A[3]; };

__global__ __launch_bounds__(512, 2)
void front_k(G1P ga, const u16* __restrict__ WBp,
             u16* __restrict__ Z1, u16* __restrict__ Z2, u16* __restrict__ Z3,
             const float* __restrict__ lam, const float* __restrict__ lam16,
             const float2* __restrict__ HcIn, float2* __restrict__ HcOut) {
    __shared__ __align__(16) float Ls[512*34];     // 69.6KB U tile, pad 34
    __shared__ float2 car[32][16];                  // [ch][st]
    __shared__ float2 hp[32][16];
    const int tid = threadIdx.x, lane = tid & 63, w = tid >> 6;
    const int b = blockIdx.x & 7, jt = blockIdx.x >> 3;   // XCD-local b
    const int l15 = lane & 15, q = lane >> 4;
    const int hb = q >> 1, hi5q = q & 1;

    f32x4 acc[4][2];
#pragma unroll
    for (int i = 0; i < 4; ++i)
#pragma unroll
        for (int n16 = 0; n16 < 2; ++n16) acc[i][n16] = 0.f;

    bf16x8 av[2][4][3], bv[2][2][3];
    auto loadA = [&](int buf, int kc) {
#pragma unroll
        for (int p = 0; p < 3; ++p)
#pragma unroll
            for (int i = 0; i < 4; ++i) {
                int m16 = i*8 + w;
                int row32 = b*16 + (m16 >> 1);
                int rin = ((m16 & 1) << 4) + l15;
                av[buf][i][p] = *(const bf16x8*)(ga.A[p]
                    + ((((size_t)(row32*8 + kc)*2 + hb)*2 + hi5q) << 8) + rin*8);
            }
    };
    auto loadB = [&](int buf, int kc) {
#pragma unroll
        for (int p = 0; p < 3; ++p)
#pragma unroll
            for (int n16 = 0; n16 < 2; ++n16)
                bv[buf][n16][p] = *(const bf16x8*)(WBp + (size_t)p*PS_WB
                    + ((((size_t)(jt*8 + kc)*2 + hb)*2 + hi5q) << 8) + (n16*16 + l15)*8);
    };

    loadA(0, 0); loadB(0, 0);
    loadA(1, 1); loadB(1, 1);
#pragma unroll
    for (int kc = 0; kc < 8; ++kc) {
        const int cb = kc & 1;
#pragma unroll
        for (int t6 = 0; t6 < 6; ++t6)
#pragma unroll
            for (int i = 0; i < 4; ++i)
#pragma unroll
                for (int n16 = 0; n16 < 2; ++n16)
                    acc[i][n16] = __builtin_amdgcn_mfma_f32_16x16x32_bf16(
                        av[cb][i][cPI[t6]], bv[cb][n16][cPJ[t6]], acc[i][n16], 0, 0, 0);
        if (kc + 2 < 8) { loadA(cb, kc + 2); loadB(cb, kc + 2); }
    }

    // deposit U tile to LDS. D-layout (16x16): col=l15, row=q*4+r
#pragma unroll
    for (int i = 0; i < 4; ++i) {
        int m16 = i*8 + w;
#pragma unroll
        for (int n16 = 0; n16 < 2; ++n16)
#pragma unroll
            for (int r = 0; r < 4; ++r) {
                int s = m16*16 + q*4 + r;
                int jl = n16*16 + l15;
                Ls[s*34 + jl] = acc[i][n16][r];
            }
    }
    __syncthreads();

    // pass 1: chunk-local carries. 512 threads: st = tid&15, ch = tid>>4 (0..31)
    {
        int st = tid & 15, ch = tid >> 4;
        int n = jt*16 + st;
        float lre = lam[2*n], lim = lam[2*n+1];
        float hr = 0.f, hm = 0.f;
#pragma unroll
        for (int t = 0; t < 16; ++t) {
            int s = ch*16 + t;
            float2 u = *(const float2*)&Ls[s*34 + 2*st];
            float nr = fmaf(lre, hr, fmaf(-lim, hm, u.x));
            float nm = fmaf(lre, hm, fmaf( lim, hr, u.y));
            hr = nr; hm = nm;
        }
        car[ch][st] = make_float2(hr, hm);
    }
    __syncthreads();

    // prefix: 16 threads, chain over 32 chunks with lambda^16
    if (tid < 16) {
        int st = tid, n = jt*16 + st;
        float l16r = lam16[2*n], l16i = lam16[2*n+1];
        float2 hh = HcIn[(size_t)b*STATE + n];
        hp[0][st] = hh;
#pragma unroll
        for (int ch = 1; ch < 32; ++ch) {
            float2 cj = car[ch-1][st];
            float nr = fmaf(l16r, hh.x, fmaf(-l16i, hh.y, cj.x));
            float ni = fmaf(l16r, hh.y, fmaf( l16i, hh.x, cj.y));
            hh.x = nr; hh.y = ni;
            hp[ch][st] = hh;
        }
    }
    __syncthreads();

    // pass 2: re-run recurrence from prefix, split3, emit Z frag-ordered
    {
        int st = tid & 15, ch = tid >> 4;
        int n = jt*16 + st;
        float lre = lam[2*n], lim = lam[2*n+1];
        float2 hh = hp[ch][st];
        int j0 = jt*32 + 2*st;
#pragma unroll
        for (int t = 0; t < 16; ++t) {
            int s = ch*16 + t;
            float2 u = *(const float2*)&Ls[s*34 + 2*st];
            float nr = fmaf(lre, hh.x, fmaf(-lim, hh.y, u.x));
            float ni = fmaf(lre, hh.y, fmaf( lim, hh.x, u.y));
            hh.x = nr; hh.y = ni;
            u16 a1,a2,a3, c1,c2,c3;
            split3(nr, a1,a2,a3);
            split3(ni, c1,c2,c3);
            size_t zo = a_idx(b*512 + s, j0, 24);
            ushort2 t2;
            t2.x = a1; t2.y = c1; *(ushort2*)(Z1 + zo) = t2;
            t2.x = a2; t2.y = c2; *(ushort2*)(Z2 + zo) = t2;
            t2.x = a3; t2.y = c3; *(ushort2*)(Z3 + zo) = t2;
        }
        if (ch == 31) HcOut[(size_t)b*STATE + n] = hh;
    }
}

// ---------------- GEMM2: 8 waves, intra-block K-split (kg=0: chunks 0-15,
// kg=1: 16-31). A (Z/X frag-ordered) and B global->reg; no K-loop barriers.
// End: LDS reduction + split3 epilogue + out.   [R11 — known good]
struct G2P {
    const u16* Z[3]; const u16* X[3]; const u16* WC; const u16* WD;
    u16* O1; u16* O2; u16* O3; float* outp; int iter;
};

__global__ __launch_bounds__(512, 2)
void gemm2_k(G2P g) {
    __shared__ __align__(16) float Lred[64*64];  // 16KB
    const int tid = threadIdx.x, lane = tid & 63, w = tid >> 6;   // w 0..7
    const int kg = w >> 2, wq = w & 3;
    const int wr = wq & 1, wcq = wq >> 1;
    const int m0 = blockIdx.x*64, n0 = blockIdx.y*64;
    const int hi5 = lane >> 5, lo5 = lane & 31;
    const int c32 = (n0 >> 5) + wcq;
    const int m32 = blockIdx.x*2 + wr;
    const int cbase = kg*16;

    typedef __attribute__((ext_vector_type(16))) float f32x16_t;
    f32x16_t accv;
#pragma unroll
    for (int i = 0; i < 16; ++i) accv[i] = 0.f;

    auto aptr = [&](int p, int c, int h) -> const u16* {
        if (c < 24)
            return g.Z[p] + ((((size_t)(m32*24 + c)*2 + h)*2 + hi5) << 8) + lo5*8;
        return g.X[p] + ((((size_t)(m32*8 + (c - 24))*2 + h)*2 + hi5) << 8) + lo5*8;
    };
    auto bptr = [&](int p, int c, int h) -> const u16* {
        if (c < 24)
            return g.WC + (size_t)p*PS_WC
                   + ((((size_t)(c32*24 + c)*2 + h)*2 + hi5) << 8) + lo5*8;
        return g.WD + (size_t)p*PS_WD
               + ((((size_t)(c32*8 + (c - 24))*2 + h)*2 + hi5) << 8) + lo5*8;
    };

    bf16x8 bwin[3][4][2];
    auto loadB = [&](int wnd, int tlo, int thi) {
#pragma unroll
        for (int p = 0; p < 3; ++p)
#pragma unroll
            for (int t = 0; t < 4; ++t) {
                if (t < tlo || t >= thi) continue;
#pragma unroll
                for (int h = 0; h < 2; ++h)
                    bwin[p][t][h] = *(const bf16x8*)bptr(p, cbase + wnd*4 + t, h);
            }
    };
    bf16x8 av[2][3][2];
    auto loadA = [&](int buf, int t) {
#pragma unroll
        for (int p = 0; p < 3; ++p)
#pragma unroll
            for (int h = 0; h < 2; ++h)
                av[buf][p][h] = *(const bf16x8*)aptr(p, cbase + t, h);
    };

    loadA(0, 0);
    loadB(0, 0, 4);
    loadA(1, 1);
#pragma unroll
    for (int t = 0; t < 16; ++t) {
        if ((t & 3) == 2 && t < 12) loadB((t >> 2) + 1, 0, 2);
        const int cb = t & 1;
        const int tw = t & 3;
#pragma unroll
        for (int t6 = 0; t6 < 6; ++t6)
            accv = __builtin_amdgcn_mfma_f32_32x32x16_bf16(
                av[cb][cPI[t6]][0], bwin[cPJ[t6]][tw][0],
                __builtin_amdgcn_mfma_f32_32x32x16_bf16(
                    av[cb][cPI[t6]][1], bwin[cPJ[t6]][tw][1], accv, 0, 0, 0),
                0, 0, 0);
        if ((t & 3) == 3 && t < 12) loadB((t >> 2) + 1, 2, 4);
        if (t + 2 < 16) loadA(cb, t + 2);
    }

    // kg=1 waves deposit partials; kg=0 waves sum + epilogue
    if (kg == 1) {
#pragma unroll
        for (int reg = 0; reg < 16; ++reg) {
            int rl = wr*32 + (reg & 3) + 8*(reg >> 2) + 4*hi5;
            int cl = wcq*32 + lo5;
            Lred[rl*64 + cl] = accv[reg];
        }
    }
    __syncthreads();
    if (kg == 0) {
#pragma unroll
        for (int reg = 0; reg < 16; ++reg) {
            int rl = wr*32 + (reg & 3) + 8*(reg >> 2) + 4*hi5;
            int cl = wcq*32 + lo5;
            float v = accv[reg] + Lred[rl*64 + cl];
            int row = m0 + rl, col = n0 + cl;
            u16 a,b,c; split3(v, a,b,c);
            size_t o = a_idx(row, col, 8);
            g.O1[o] = a; g.O2[o] = b; g.O3[o] = c;
            if ((row & (SEQ-1)) == SEQ-1)
                g.outp[(size_t)((row >> 9)*OUT_SEQ + g.iter)*IN_CH + col] = v;
        }
    }
}

// ---------------- launch ----------------
extern "C" void kernel_launch(void* const* d_in, const int* in_sizes, int n_in,
                              void* d_out, int out_size, void* d_ws, size_t ws_size,
                              hipStream_t stream) {
    const float* x_in      = (const float*)d_in[0];
    const float* nu_log    = (const float*)d_in[1];
    const float* theta_log = (const float*)d_in[2];
    const float* gamma_log = (const float*)d_in[3];
    const float* B_re      = (const float*)d_in[4];
    const float* B_im      = (const float*)d_in[5];
    const float* C_re      = (const float*)d_in[6];
    const float* C_im      = (const float*)d_in[7];
    const float* D         = (const float*)d_in[8];
    float* out = (float*)d_out;

    char* ws = (char*)d_ws;
    u16* Z1 = (u16*)(ws + B_Z);
    u16* Z2 = Z1 + PS_Z;
    u16* Z3 = Z2 + PS_Z;
    u16* XA1 = (u16*)(ws + B_XA);
    u16* XA2 = XA1 + PS_X;
    u16* XA3 = XA2 + PS_X;
    u16* XB1 = (u16*)(ws + B_XB);
    u16* XB2 = XB1 + PS_X;
    u16* XB3 = XB2 + PS_X;
    u16* WB  = (u16*)(ws + B_WB);
    u16* WCt = (u16*)(ws + B_WC);
    u16* WDt = (u16*)(ws + B_WD);
    float* lam   = (float*)(ws + B_LAM);
    float* lam16 = lam + 768;
    float2* Hc0  = (float2*)(ws + B_HC);
    float2* Hc1  = Hc0 + (size_t)B_SZ*STATE;

    prep_lam_hc<<<1, 384, 0, stream>>>(nu_log, theta_log, lam, lam16, (float*)Hc0);
    prep_wb<<<PS_WB/256, 256, 0, stream>>>(B_re, B_im, gamma_log, WB);
    prep_wcd<<<(PS_WC + PS_WD)/256, 256, 0, stream>>>(C_re, C_im, D, WCt, WDt);
    prep_x<<<(M_ROWS*IN_CH)/256, 256, 0, stream>>>(x_in, XA1, XA2, XA3);

    for (int it = 0; it < OUT_SEQ; ++it) {
        u16* Xc[3]; u16* Xn[3];
        if (it & 1) { Xc[0]=XB1; Xc[1]=XB2; Xc[2]=XB3; Xn[0]=XA1; Xn[1]=XA2; Xn[2]=XA3; }
        else        { Xc[0]=XA1; Xc[1]=XA2; Xc[2]=XA3; Xn[0]=XB1; Xn[1]=XB2; Xn[2]=XB3; }
        float2* Hin  = (it & 1) ? Hc1 : Hc0;
        float2* Hout = (it & 1) ? Hc0 : Hc1;

        // FRONT: gemm1 (LDS U) + scan + Z emit + HcOut (XCD-swizzled grid)
        G1P g1;
        for (int p = 0; p < 3; ++p) g1.A[p] = Xc[p];
        front_k<<<192, 512, 0, stream>>>(
            g1, WB, Z1, Z2, Z3, lam, lam16, Hin, Hout);

        // GEMM2: 8-wave intra-block K-split, epilogue writes Xn frags + out
        G2P g2;
        g2.Z[0]=Z1; g2.Z[1]=Z2; g2.Z[2]=Z3;
        g2.X[0]=Xc[0]; g2.X[1]=Xc[1]; g2.X[2]=Xc[2];
        g2.WC = WCt; g2.WD = WDt;
        g2.O1 = Xn[0]; g2.O2 = Xn[1]; g2.O3 = Xn[2];
        g2.outp = out; g2.iter = it;
        gemm2_k<<<dim3(M_ROWS/64, IN_CH/64), 512, 0, stream>>>(g2);
    }
}

// Round 14
// 1261.680 us; speedup vs baseline: 6.4903x; 1.0544x over previous
//
#include <hip/hip_runtime.h>
#include <hip/hip_bf16.h>
#include <math.h>

typedef unsigned short u16;
typedef __attribute__((ext_vector_type(8))) short bf16x8;
typedef __attribute__((ext_vector_type(4))) float f32x4;
typedef __attribute__((ext_vector_type(16))) float f32x16;

#define IN_CH   256
#define STATE   384
#define OUT_SEQ 32
#define B_SZ    8
#define SEQ     512
#define M_ROWS  4096
#define NJ      768   // 2*STATE

// plane sizes (elements)
#define PS_WB  (NJ*IN_CH)      // 196608
#define PS_WC  (IN_CH*NJ)      // 196608
#define PS_WD  (IN_CH*IN_CH)   // 65536
#define PS_Z   ((size_t)M_ROWS*NJ)
#define PS_X   ((size_t)M_ROWS*IN_CH)

// ---------------- workspace layout (bytes) ----------------
static constexpr size_t B_U   = 0;                                   // P partial (4MB used)
static constexpr size_t B_Z   = B_U  + 8*(size_t)M_ROWS*IN_CH*4;
static constexpr size_t B_XA  = B_Z  + 3*(size_t)M_ROWS*NJ*2;
static constexpr size_t B_XB  = B_XA + 3*(size_t)M_ROWS*IN_CH*2;
static constexpr size_t B_WB  = B_XB + 3*(size_t)M_ROWS*IN_CH*2;
static constexpr size_t B_WC  = B_WB + 3*(size_t)PS_WB*2;
static constexpr size_t B_WD  = B_WC + 3*(size_t)PS_WC*2;
static constexpr size_t B_LAM = B_WD + 3*(size_t)PS_WD*2;            // lam, lam16
static constexpr size_t B_HC  = B_LAM + 2*768*4;                     // Hc0, Hc1

// ---------------- helpers ----------------
__device__ __forceinline__ u16 f2b(float v) {
    __hip_bfloat16 h = __float2bfloat16(v);
    return *(u16*)&h;
}
__device__ __forceinline__ float b2f(u16 u) {
    __hip_bfloat16 h = *(__hip_bfloat16*)&u;
    return __bfloat162float(h);
}
__device__ __forceinline__ void split3(float v, u16& a, u16& b, u16& c) {
    a = f2b(v);  float r1 = v  - b2f(a);
    b = f2b(r1); float r2 = r1 - b2f(b);
    c = f2b(r2);
}

// A-fragment-ordered (32x32-family) plane index: element (row, k), NKC = K/32.
__device__ __forceinline__ size_t a_idx(int row, int k, int NKC) {
    return ((size_t)(((row >> 5)*NKC + (k >> 5))*2 + ((k >> 4) & 1))*2 + ((k >> 3) & 1))*256
           + (size_t)(row & 31)*8 + (k & 7);
}

// fragment-index decode for weight prep: r -> (t32,h,hi5,lo5,e)
__device__ __forceinline__ void frag_decode(int r, int& t32, int& h, int& hi5,
                                            int& lo5, int& e) {
    t32 = r >> 10; int r2 = r & 1023;
    h = r2 >> 9;   int r3 = r2 & 511;
    hi5 = r3 >> 8; int r4 = r3 & 255;
    lo5 = r4 >> 3; e = r4 & 7;
}

// ---------------- prep kernels ----------------
__global__ void prep_lam_hc(const float* __restrict__ nu_log,
                            const float* __restrict__ th_log,
                            float* __restrict__ lam, float* __restrict__ lam16,
                            float* __restrict__ hc0) {
    int n = threadIdx.x;
    if (n < STATE) {
        float lm = expf(-expf(nu_log[n]));
        float th = expf(th_log[n]);
        float ar = lm * cosf(th), ai = lm * sinf(th);
        lam[2*n] = ar; lam[2*n+1] = ai;
        float pr = ar, pi = ai;
#pragma unroll
        for (int i = 0; i < 4; ++i) {   // lambda^16
            float nr = pr*pr - pi*pi, ni = 2.f*pr*pi;
            pr = nr; pi = ni;
        }
        lam16[2*n] = pr; lam16[2*n+1] = pi;
    }
    for (int i = threadIdx.x; i < B_SZ*NJ; i += blockDim.x) hc0[i] = 0.f;
}

__global__ void prep_wb(const float* __restrict__ B_re, const float* __restrict__ B_im,
                        const float* __restrict__ gamma_log, u16* __restrict__ W) {
    int idx = blockIdx.x*blockDim.x + threadIdx.x;   // < 196608
    int c32 = idx >> 13, r = idx & 8191;
    int t32,h,hi5,lo5,e; frag_decode(r, t32,h,hi5,lo5,e);
    int j = c32*32 + lo5;
    int k = t32*32 + (2*h + hi5)*8 + e;
    int n = j >> 1;
    float g = expf(gamma_log[n]);
    float v = g * ((j & 1) ? B_im[n*IN_CH + k] : B_re[n*IN_CH + k]);
    u16 a,b,cc; split3(v,a,b,cc);
    W[idx] = a; W[idx + PS_WB] = b; W[idx + 2*PS_WB] = cc;
}

__global__ void prep_wcd(const float* __restrict__ C_re, const float* __restrict__ C_im,
                         const float* __restrict__ D,
                         u16* __restrict__ WC, u16* __restrict__ WD) {
    int idx = blockIdx.x*blockDim.x + threadIdx.x;   // < 196608 + 65536
    if (idx < PS_WC) {
        int c32 = idx / 24576, r = idx % 24576;
        int t32,h,hi5,lo5,e; frag_decode(r, t32,h,hi5,lo5,e);
        int o = c32*32 + lo5;
        int j = t32*32 + (2*h + hi5)*8 + e;
        int n = j >> 1;
        float v = (j & 1) ? -C_im[o*STATE + n] : C_re[o*STATE + n];
        u16 a,b,c; split3(v,a,b,c);
        WC[idx] = a; WC[idx + PS_WC] = b; WC[idx + 2*PS_WC] = c;
    } else {
        int q = idx - PS_WC;
        int c32 = q >> 13, r = q & 8191;
        int t32,h,hi5,lo5,e; frag_decode(r, t32,h,hi5,lo5,e);
        int o = c32*32 + lo5;
        int c = t32*32 + (2*h + hi5)*8 + e;
        float v = D[o*IN_CH + c];
        u16 a,b,cc; split3(v,a,b,cc);
        WD[q] = a; WD[q + PS_WD] = b; WD[q + 2*PS_WD] = cc;
    }
}

// X planes fragment-ordered (NKC=8)
__global__ void prep_x(const float* __restrict__ x,
                       u16* __restrict__ X1, u16* __restrict__ X2, u16* __restrict__ X3) {
    int idx = blockIdx.x*blockDim.x + threadIdx.x;   // < 4096*256
    int row = idx >> 8, k = idx & 255;
    u16 a,b,c; split3(x[idx],a,b,c);
    size_t o = a_idx(row, k, 8);
    X1[o] = a; X2[o] = b; X3[o] = c;
}

// product order for bf16x3 (large terms first)
__device__ __constant__ const int cPI[6] = {0,0,1,0,1,2};
__device__ __constant__ const int cPJ[6] = {0,1,0,2,1,0};

// ---------------- FRONT: blocks 0..191: U (LDS) + scan + Z emit; blocks
// 192..255: P = X*WD^T partial (fp32). 512 threads (8 waves).
struct G1P { const u16* A[3]; };

__global__ __launch_bounds__(512, 2)
void front_k(G1P ga, const u16* __restrict__ WBp, const u16* __restrict__ WDp,
             u16* __restrict__ Z1, u16* __restrict__ Z2, u16* __restrict__ Z3,
             float* __restrict__ P,
             const float* __restrict__ lam, const float* __restrict__ lam16,
             const float2* __restrict__ HcIn, float2* __restrict__ HcOut) {
    __shared__ __align__(16) float Ls[512*34];     // 69.6KB U tile (front job)
    __shared__ float2 car[32][16];
    __shared__ float2 hp[32][16];
    const int tid = threadIdx.x, lane = tid & 63, w = tid >> 6;
    const int l15 = lane & 15, q = lane >> 4;
    const int hb = q >> 1, hi5q = q & 1;
    const int hi5 = lane >> 5, lo5 = lane & 31;

    if (blockIdx.x >= 192) {
        // ---------- WD job: P[mt rows][256 cols] = sum_6 X_pi * WD_pj^T ----------
        const int mt = blockIdx.x - 192;          // 0..63
        const int wr = w & 1, wc = w >> 1;        // wc 0..3 -> cols wc*64
        const int m32 = mt*2 + wr;
        f32x16 acc[2];
#pragma unroll
        for (int cj = 0; cj < 2; ++cj)
#pragma unroll
            for (int i = 0; i < 16; ++i) acc[cj][i] = 0.f;

        bf16x8 av[2][3][2], bv[2][2][3][2];
        auto loadA = [&](int buf, int kc) {
#pragma unroll
            for (int p = 0; p < 3; ++p)
#pragma unroll
                for (int h = 0; h < 2; ++h)
                    av[buf][p][h] = *(const bf16x8*)(ga.A[p]
                        + ((((size_t)(m32*8 + kc)*2 + h)*2 + hi5) << 8) + lo5*8);
        };
        auto loadB = [&](int buf, int kc) {
#pragma unroll
            for (int cj = 0; cj < 2; ++cj)
#pragma unroll
                for (int p = 0; p < 3; ++p)
#pragma unroll
                    for (int h = 0; h < 2; ++h)
                        bv[buf][cj][p][h] = *(const bf16x8*)(WDp + (size_t)p*PS_WD
                            + ((((size_t)((wc*2 + cj)*8 + kc)*2 + h)*2 + hi5) << 8) + lo5*8);
        };
        loadA(0, 0); loadB(0, 0);
        loadA(1, 1); loadB(1, 1);
#pragma unroll
        for (int kc = 0; kc < 8; ++kc) {
            const int cb = kc & 1;
#pragma unroll
            for (int t6 = 0; t6 < 6; ++t6)
#pragma unroll
                for (int cj = 0; cj < 2; ++cj)
#pragma unroll
                    for (int h = 0; h < 2; ++h)
                        acc[cj] = __builtin_amdgcn_mfma_f32_32x32x16_bf16(
                            av[cb][cPI[t6]][h], bv[cb][cj][cPJ[t6]][h], acc[cj], 0, 0, 0);
            if (kc + 2 < 8) { loadA(cb, kc + 2); loadB(cb, kc + 2); }
        }
#pragma unroll
        for (int cj = 0; cj < 2; ++cj)
#pragma unroll
            for (int reg = 0; reg < 16; ++reg) {
                int row = mt*64 + wr*32 + (reg & 3) + 8*(reg >> 2) + 4*hi5;
                int col = wc*64 + cj*32 + lo5;
                P[(size_t)row*IN_CH + col] = acc[cj][reg];
            }
        return;
    }

    // ---------- front job ----------
    const int b = blockIdx.x & 7, jt = blockIdx.x >> 3;   // XCD-local b

    f32x4 acc[4][2];
#pragma unroll
    for (int i = 0; i < 4; ++i)
#pragma unroll
        for (int n16 = 0; n16 < 2; ++n16) acc[i][n16] = 0.f;

    bf16x8 av[2][4][3], bv[2][2][3];
    auto loadA = [&](int buf, int kc) {
#pragma unroll
        for (int p = 0; p < 3; ++p)
#pragma unroll
            for (int i = 0; i < 4; ++i) {
                int m16 = i*8 + w;
                int row32 = b*16 + (m16 >> 1);
                int rin = ((m16 & 1) << 4) + l15;
                av[buf][i][p] = *(const bf16x8*)(ga.A[p]
                    + ((((size_t)(row32*8 + kc)*2 + hb)*2 + hi5q) << 8) + rin*8);
            }
    };
    auto loadB = [&](int buf, int kc) {
#pragma unroll
        for (int p = 0; p < 3; ++p)
#pragma unroll
            for (int n16 = 0; n16 < 2; ++n16)
                bv[buf][n16][p] = *(const bf16x8*)(WBp + (size_t)p*PS_WB
                    + ((((size_t)(jt*8 + kc)*2 + hb)*2 + hi5q) << 8) + (n16*16 + l15)*8);
    };

    loadA(0, 0); loadB(0, 0);
    loadA(1, 1); loadB(1, 1);
#pragma unroll
    for (int kc = 0; kc < 8; ++kc) {
        const int cb = kc & 1;
#pragma unroll
        for (int t6 = 0; t6 < 6; ++t6)
#pragma unroll
            for (int i = 0; i < 4; ++i)
#pragma unroll
                for (int n16 = 0; n16 < 2; ++n16)
                    acc[i][n16] = __builtin_amdgcn_mfma_f32_16x16x32_bf16(
                        av[cb][i][cPI[t6]], bv[cb][n16][cPJ[t6]], acc[i][n16], 0, 0, 0);
        if (kc + 2 < 8) { loadA(cb, kc + 2); loadB(cb, kc + 2); }
    }

    // deposit U tile to LDS. D-layout (16x16): col=l15, row=q*4+r
#pragma unroll
    for (int i = 0; i < 4; ++i) {
        int m16 = i*8 + w;
#pragma unroll
        for (int n16 = 0; n16 < 2; ++n16)
#pragma unroll
            for (int r = 0; r < 4; ++r) {
                int s = m16*16 + q*4 + r;
                int jl = n16*16 + l15;
                Ls[s*34 + jl] = acc[i][n16][r];
            }
    }
    __syncthreads();

    // pass 1: chunk-local carries. st = tid&15, ch = tid>>4 (0..31), 16 steps
    {
        int st = tid & 15, ch = tid >> 4;
        int n = jt*16 + st;
        float lre = lam[2*n], lim = lam[2*n+1];
        float hr = 0.f, hm = 0.f;
#pragma unroll
        for (int t = 0; t < 16; ++t) {
            int s = ch*16 + t;
            float2 u = *(const float2*)&Ls[s*34 + 2*st];
            float nr = fmaf(lre, hr, fmaf(-lim, hm, u.x));
            float nm = fmaf(lre, hm, fmaf( lim, hr, u.y));
            hr = nr; hm = nm;
        }
        car[ch][st] = make_float2(hr, hm);
    }
    __syncthreads();

    // parallel prefix over 32 chunks (complex affine maps), all waves.
    // mapping: st2 = 2*w + (lane>>5), ch2 = lane&31
    {
        int st2 = 2*w + hi5, ch2 = lane & 31;
        int n = jt*16 + st2;
        float2 e = car[ch2][st2];
        float Ar = lam16[2*n], Ai = lam16[2*n+1];
        float Br = e.x, Bi = e.y;
#pragma unroll
        for (int d = 1; d < 32; d <<= 1) {
            int src = (lane & 32) | ((lane - d) & 31);
            float pAr = __shfl(Ar, src), pAi = __shfl(Ai, src);
            float pBr = __shfl(Br, src), pBi = __shfl(Bi, src);
            if (ch2 >= d) {
                float nAr = Ar*pAr - Ai*pAi;
                float nAi = Ar*pAi + Ai*pAr;
                float nBr = fmaf(Ar, pBr, fmaf(-Ai, pBi, Br));
                float nBi = fmaf(Ar, pBi, fmaf( Ai, pBr, Bi));
                Ar = nAr; Ai = nAi; Br = nBr; Bi = nBi;
            }
        }
        float2 s0 = HcIn[(size_t)b*STATE + n];
        // final state after all 32 chunks (inclusive at ch2==31)
        if (ch2 == 31) {
            float fr = fmaf(Ar, s0.x, fmaf(-Ai, s0.y, Br));
            float fi = fmaf(Ar, s0.y, fmaf( Ai, s0.x, Bi));
            HcOut[(size_t)b*STATE + n] = make_float2(fr, fi);
        }
        // exclusive: shift inclusive by one chunk
        int srcp = (lane & 32) | ((lane - 1) & 31);
        float eAr = __shfl(Ar, srcp), eAi = __shfl(Ai, srcp);
        float eBr = __shfl(Br, srcp), eBi = __shfl(Bi, srcp);
        float sr, si;
        if (ch2 == 0) { sr = s0.x; si = s0.y; }
        else {
            sr = fmaf(eAr, s0.x, fmaf(-eAi, s0.y, eBr));
            si = fmaf(eAr, s0.y, fmaf( eAi, s0.x, eBi));
        }
        hp[ch2][st2] = make_float2(sr, si);
    }
    __syncthreads();

    // pass 2: re-run recurrence from prefix, split3, emit Z frag-ordered
    {
        int st = tid & 15, ch = tid >> 4;
        int n = jt*16 + st;
        float lre = lam[2*n], lim = lam[2*n+1];
        float2 hh = hp[ch][st];
        int j0 = jt*32 + 2*st;
#pragma unroll
        for (int t = 0; t < 16; ++t) {
            int s = ch*16 + t;
            float2 u = *(const float2*)&Ls[s*34 + 2*st];
            float nr = fmaf(lre, hh.x, fmaf(-lim, hh.y, u.x));
            float ni = fmaf(lre, hh.y, fmaf( lim, hh.x, u.y));
            hh.x = nr; hh.y = ni;
            u16 a1,a2,a3, c1,c2,c3;
            split3(nr, a1,a2,a3);
            split3(ni, c1,c2,c3);
            size_t zo = a_idx(b*512 + s, j0, 24);
            ushort2 t2;
            t2.x = a1; t2.y = c1; *(ushort2*)(Z1 + zo) = t2;
            t2.x = a2; t2.y = c2; *(ushort2*)(Z2 + zo) = t2;
            t2.x = a3; t2.y = c3; *(ushort2*)(Z3 + zo) = t2;
        }
    }
}

// ---------------- GEMM2: Z*WC^T only (K=768), kg-split 2x12 chunks; acc
// init 0, epilogue adds Lred + P. A/B frag-ordered global->reg, no barriers.
struct G2P {
    const u16* Z[3]; const u16* WC; const float* P;
    u16* O1; u16* O2; u16* O3; float* outp; int iter;
};

__global__ __launch_bounds__(512, 2)
void gemm2_k(G2P g) {
    __shared__ __align__(16) float Lred[64*64];  // 16KB
    const int tid = threadIdx.x, lane = tid & 63, w = tid >> 6;   // w 0..7
    const int kg = w >> 2, wq = w & 3;
    const int wr = wq & 1, wcq = wq >> 1;
    const int m0 = blockIdx.x*64, n0 = blockIdx.y*64;
    const int hi5 = lane >> 5, lo5 = lane & 31;
    const int c32 = (n0 >> 5) + wcq;
    const int m32 = blockIdx.x*2 + wr;
    const int cbase = kg*12;

    f32x16 accv;
#pragma unroll
    for (int i = 0; i < 16; ++i) accv[i] = 0.f;

    auto aptr = [&](int p, int c, int h) -> const u16* {
        return g.Z[p] + ((((size_t)(m32*24 + c)*2 + h)*2 + hi5) << 8) + lo5*8;
    };
    auto bptr = [&](int p, int c, int h) -> const u16* {
        return g.WC + (size_t)p*PS_WC
               + ((((size_t)(c32*24 + c)*2 + h)*2 + hi5) << 8) + lo5*8;
    };

    bf16x8 bwin[3][4][2];
    auto loadB = [&](int wnd, int tlo, int thi) {
#pragma unroll
        for (int p = 0; p < 3; ++p)
#pragma unroll
            for (int t = 0; t < 4; ++t) {
                if (t < tlo || t >= thi) continue;
#pragma unroll
                for (int h = 0; h < 2; ++h)
                    bwin[p][t][h] = *(const bf16x8*)bptr(p, cbase + wnd*4 + t, h);
            }
    };
    bf16x8 av[2][3][2];
    auto loadA = [&](int buf, int t) {
#pragma unroll
        for (int p = 0; p < 3; ++p)
#pragma unroll
            for (int h = 0; h < 2; ++h)
                av[buf][p][h] = *(const bf16x8*)aptr(p, cbase + t, h);
    };

    loadA(0, 0);
    loadB(0, 0, 4);
    loadA(1, 1);
#pragma unroll
    for (int t = 0; t < 12; ++t) {
        if ((t & 3) == 2 && t < 8) loadB((t >> 2) + 1, 0, 2);
        const int cb = t & 1;
        const int tw = t & 3;
#pragma unroll
        for (int t6 = 0; t6 < 6; ++t6)
            accv = __builtin_amdgcn_mfma_f32_32x32x16_bf16(
                av[cb][cPI[t6]][0], bwin[cPJ[t6]][tw][0],
                __builtin_amdgcn_mfma_f32_32x32x16_bf16(
                    av[cb][cPI[t6]][1], bwin[cPJ[t6]][tw][1], accv, 0, 0, 0),
                0, 0, 0);
        if ((t & 3) == 3 && t < 8) loadB((t >> 2) + 1, 2, 4);
        if (t + 2 < 12) loadA(cb, t + 2);
    }

    // kg=1 waves deposit partials; kg=0 waves sum + P + epilogue
    if (kg == 1) {
#pragma unroll
        for (int reg = 0; reg < 16; ++reg) {
            int rl = wr*32 + (reg & 3) + 8*(reg >> 2) + 4*hi5;
            int cl = wcq*32 + lo5;
            Lred[rl*64 + cl] = accv[reg];
        }
    }
    __syncthreads();
    if (kg == 0) {
#pragma unroll
        for (int reg = 0; reg < 16; ++reg) {
            int rl = wr*32 + (reg & 3) + 8*(reg >> 2) + 4*hi5;
            int cl = wcq*32 + lo5;
            int row = m0 + rl, col = n0 + cl;
            float v = accv[reg] + Lred[rl*64 + cl] + g.P[(size_t)row*IN_CH + col];
            u16 a,b,c; split3(v, a,b,c);
            size_t o = a_idx(row, col, 8);
            g.O1[o] = a; g.O2[o] = b; g.O3[o] = c;
            if ((row & (SEQ-1)) == SEQ-1)
                g.outp[(size_t)((row >> 9)*OUT_SEQ + g.iter)*IN_CH + col] = v;
        }
    }
}

// ---------------- launch ----------------
extern "C" void kernel_launch(void* const* d_in, const int* in_sizes, int n_in,
                              void* d_out, int out_size, void* d_ws, size_t ws_size,
                              hipStream_t stream) {
    const float* x_in      = (const float*)d_in[0];
    const float* nu_log    = (const float*)d_in[1];
    const float* theta_log = (const float*)d_in[2];
    const float* gamma_log = (const float*)d_in[3];
    const float* B_re      = (const float*)d_in[4];
    const float* B_im      = (const float*)d_in[5];
    const float* C_re      = (const float*)d_in[6];
    const float* C_im      = (const float*)d_in[7];
    const float* D         = (const float*)d_in[8];
    float* out = (float*)d_out;

    char* ws = (char*)d_ws;
    float* P = (float*)(ws + B_U);                 // [4096][256] fp32 partial
    u16* Z1 = (u16*)(ws + B_Z);
    u16* Z2 = Z1 + PS_Z;
    u16* Z3 = Z2 + PS_Z;
    u16* XA1 = (u16*)(ws + B_XA);
    u16* XA2 = XA1 + PS_X;
    u16* XA3 = XA2 + PS_X;
    u16* XB1 = (u16*)(ws + B_XB);
    u16* XB2 = XB1 + PS_X;
    u16* XB3 = XB2 + PS_X;
    u16* WB  = (u16*)(ws + B_WB);
    u16* WCt = (u16*)(ws + B_WC);
    u16* WDt = (u16*)(ws + B_WD);
    float* lam   = (float*)(ws + B_LAM);
    float* lam16 = lam + 768;
    float2* Hc0  = (float2*)(ws + B_HC);
    float2* Hc1  = Hc0 + (size_t)B_SZ*STATE;

    prep_lam_hc<<<1, 384, 0, stream>>>(nu_log, theta_log, lam, lam16, (float*)Hc0);
    prep_wb<<<PS_WB/256, 256, 0, stream>>>(B_re, B_im, gamma_log, WB);
    prep_wcd<<<(PS_WC + PS_WD)/256, 256, 0, stream>>>(C_re, C_im, D, WCt, WDt);
    prep_x<<<(M_ROWS*IN_CH)/256, 256, 0, stream>>>(x_in, XA1, XA2, XA3);

    for (int it = 0; it < OUT_SEQ; ++it) {
        u16* Xc[3]; u16* Xn[3];
        if (it & 1) { Xc[0]=XB1; Xc[1]=XB2; Xc[2]=XB3; Xn[0]=XA1; Xn[1]=XA2; Xn[2]=XA3; }
        else        { Xc[0]=XA1; Xc[1]=XA2; Xc[2]=XA3; Xn[0]=XB1; Xn[1]=XB2; Xn[2]=XB3; }
        float2* Hin  = (it & 1) ? Hc1 : Hc0;
        float2* Hout = (it & 1) ? Hc0 : Hc1;

        // FRONT: U+scan+Z emit (192 blocks) and P = X*WD^T (64 blocks)
        G1P g1;
        for (int p = 0; p < 3; ++p) g1.A[p] = Xc[p];
        front_k<<<256, 512, 0, stream>>>(
            g1, WB, WDt, Z1, Z2, Z3, P, lam, lam16, Hin, Hout);

        // GEMM2: Z*WC^T (K=768) + Lred + P -> Xn frags + out
        G2P g2;
        g2.Z[0]=Z1; g2.Z[1]=Z2; g2.Z[2]=Z3;
        g2.WC = WCt; g2.P = P;
        g2.O1 = Xn[0]; g2.O2 = Xn[1]; g2.O3 = Xn[2];
        g2.outp = out; g2.iter = it;
        gemm2_k<<<dim3(M_ROWS/64, IN_CH/64), 512, 0, stream>>>(g2);
    }
}